// Round 9
// baseline (449.497 us; speedup 1.0000x reference)
//
#include <hip/hip_runtime.h>

#define HBLK 128  // hidden width, fixed by problem

typedef __attribute__((ext_vector_type(8))) short s8v;    // 8 bf16 in 4 VGPRs
typedef __attribute__((ext_vector_type(4))) float f32x4;  // MFMA accumulator
typedef __attribute__((ext_vector_type(4))) _Float16 h4f; // 4 fp16 = 8B

// split fp32 into bf16 hi + lo (truncation; residual <= 2^-16 |x|)
__device__ inline void split2(float x, short& h, short& l) {
    unsigned hb = __float_as_uint(x) & 0xFFFF0000u;
    float hf = __uint_as_float(hb);
    float lf = x - hf;
    h = (short)(hb >> 16);
    l = (short)(__float_as_uint(lf) >> 16);
}

// ---------------- CSR build ----------------
__global__ void zero_counts(int* counts, int n) {
    int i = blockIdx.x * 256 + threadIdx.x;
    if (i < n) counts[i] = 0;
}

__global__ void hist_k(const int* __restrict__ dst, int* counts, int E) {
    int e = blockIdx.x * 256 + threadIdx.x;
    if (e < E) atomicAdd(&counts[dst[e]], 1);
}

// ---- parallel exclusive scan, 3 phases (N up to 256*256) ----
__global__ void scan1(const int* __restrict__ counts, int* __restrict__ offs,
                      int* __restrict__ bsums, int n) {
    __shared__ int lds[256];
    const int t = threadIdx.x;
    const int i = blockIdx.x * 256 + t;
    const int v = (i < n) ? counts[i] : 0;
    lds[t] = v;
    __syncthreads();
    for (int off = 1; off < 256; off <<= 1) {
        int add = (t >= off) ? lds[t - off] : 0;
        __syncthreads();
        lds[t] += add;
        __syncthreads();
    }
    if (i < n) offs[i] = lds[t] - v;          // exclusive within block
    if (t == 255) bsums[blockIdx.x] = lds[255];
}

__global__ void scan2(int* __restrict__ bsums, int nb) {
    __shared__ int lds[256];
    const int t = threadIdx.x;
    const int v = (t < nb) ? bsums[t] : 0;
    lds[t] = v;
    __syncthreads();
    for (int off = 1; off < 256; off <<= 1) {
        int add = (t >= off) ? lds[t - off] : 0;
        __syncthreads();
        lds[t] += add;
        __syncthreads();
    }
    if (t < nb) bsums[t] = lds[t] - v;        // exclusive block prefix
}

__global__ void scan3(int* __restrict__ offs, int* __restrict__ cursor,
                      const int* __restrict__ bsums, int n, int E) {
    const int i = blockIdx.x * 256 + threadIdx.x;
    if (i < n) {
        int v = offs[i] + bsums[blockIdx.x];
        offs[i] = v;
        cursor[i] = v;
    }
    if (i == 0) offs[n] = E;                  // total: every edge has a dst
}

// single scattered store: perm[p] = edge id (halves scatter writeback vs 2 arrays)
__global__ void fill_k(const int* __restrict__ dst, int* cursor,
                       int* __restrict__ perm, int E) {
    int e = blockIdx.x * 256 + threadIdx.x;
    if (e < E) {
        int p = atomicAdd(&cursor[dst[e]], 1);
        perm[p] = e;
    }
}

// ---------------- weight split + pack into MFMA-fragment order ----------------
// Chunk-major: off = ((chunk*8 + j)*64 + lane)*8 + t, so chunk c occupies
// shorts [c*4096, (c+1)*4096) — stage-able as one contiguous 8 KB block.
__global__ void split_w_pack(const float* __restrict__ W, int ldw, int kin,
                             short* __restrict__ dh, short* __restrict__ dl,
                             int C, int K) {
    long i = (long)blockIdx.x * 256 + threadIdx.x;
    if (i >= (long)C * K) return;
    int c = (int)(i / K), k = (int)(i % K);
    float x = (k < kin) ? W[(long)c * ldw + k] : 0.f;
    short h, l;
    split2(x, h, l);
    int j = c >> 4, l16 = c & 15;
    int chunk = k >> 5, quad = (k >> 3) & 3, t = k & 7;
    long off = (((long)(chunk * 8 + j) * 64) + quad * 16 + l16) * 8 + t;
    dh[off] = h;
    dl[off] = l;
}

// ---------------- split-fp32 MFMA GEMM, LDS-staged W, double-buffered ----------------
__global__ __launch_bounds__(256, 2) void gemm_mfma(
    const float* __restrict__ A1, int lda1, int K1,
    const float* __restrict__ A2, int lda2, int Kin,
    int K,
    const short* __restrict__ W1h, const short* __restrict__ W1l,
    const short* __restrict__ W2h, const short* __restrict__ W2l,
    const float* __restrict__ bias,
    float* __restrict__ C1f, float* __restrict__ C2f,
    _Float16* __restrict__ Czh,
    int M, int relu)
{
    __shared__ short lds_h[2][4096];   // 8 KB per buffer (one 32-k chunk, hi)
    __shared__ short lds_l[2][4096];   // 8 KB per buffer (lo)
    const short* __restrict__ Wh = blockIdx.y ? W2h : W1h;
    const short* __restrict__ Wl = blockIdx.y ? W2l : W1l;
    float* __restrict__ Cf = blockIdx.y ? C2f : C1f;
    _Float16* __restrict__ Ch16 = blockIdx.y ? Czh : nullptr;
    const int tid = threadIdx.x;
    const int wv = tid >> 6;
    const int lane = tid & 63;
    const int l16 = lane & 15;
    const int quad = lane >> 4;
    const int m0 = blockIdx.x * 64 + wv * 16;   // this wave's 16-row tile
    int ra = m0 + l16;
    if (ra >= M) ra = M - 1;                    // clamp loads; stores guarded
    const long r1 = (long)ra * lda1;
    const long r2 = (long)ra * lda2;
    const int NC = K >> 5;                      // 32-k chunks

    f32x4 acc[8];
#pragma unroll
    for (int j = 0; j < 8; ++j) acc[j] = (f32x4){0.f, 0.f, 0.f, 0.f};

#define LOAD_A_RAW(dst0, dst1, kb)                                              \
    {                                                                           \
        const int col0 = (kb) + quad * 8;                                       \
        if (col0 < K1) {                                                        \
            const float* ap = A1 + r1 + col0;                                   \
            dst0 = *(const float4*)ap;                                          \
            dst1 = *(const float4*)(ap + 4);                                    \
        } else if (col0 < Kin) {                                                \
            const float* ap = A2 + r2 + (col0 - K1);                            \
            dst0 = *(const float4*)ap;                                          \
            dst1 = *(const float4*)(ap + 4);                                    \
        } else {                                                                \
            dst0 = make_float4(0.f, 0.f, 0.f, 0.f);                             \
            dst1 = make_float4(0.f, 0.f, 0.f, 0.f);                             \
        }                                                                       \
    }

#define SPLIT_A(a0, a1, ah, al)                                                 \
    {                                                                           \
        float vv[8];                                                            \
        *(float4*)&vv[0] = a0;                                                  \
        *(float4*)&vv[4] = a1;                                                  \
        _Pragma("unroll")                                                       \
        for (int e = 0; e < 8; ++e) {                                           \
            short hh, ll;                                                       \
            split2(vv[e], hh, ll);                                              \
            ah[e] = hh;                                                         \
            al[e] = ll;                                                         \
        }                                                                       \
    }

    // prologue: stage chunk 0 into buffer 0 (8 KB hi + 8 KB lo; 32 B/thread each)
    {
        const int4* gh = (const int4*)Wh;
        const int4* gl = (const int4*)Wl;
        int4* bh = (int4*)lds_h[0];
        int4* bl = (int4*)lds_l[0];
        bh[tid * 2] = gh[tid * 2];
        bh[tid * 2 + 1] = gh[tid * 2 + 1];
        bl[tid * 2] = gl[tid * 2];
        bl[tid * 2 + 1] = gl[tid * 2 + 1];
    }
    float4 ac0, ac1, an0, an1;
    LOAD_A_RAW(ac0, ac1, 0)
    __syncthreads();

    for (int c = 0; c < NC; ++c) {
        const int nb = c & 1, fb = nb ^ 1;
        // prefetch next W chunk global -> regs
        int4 nh0, nh1, nl0, nl1;
        const bool more = (c + 1 < NC);
        if (more) {
            const int4* gh = (const int4*)(Wh + (long)(c + 1) * 4096);
            const int4* gl = (const int4*)(Wl + (long)(c + 1) * 4096);
            nh0 = gh[tid * 2];
            nh1 = gh[tid * 2 + 1];
            nl0 = gl[tid * 2];
            nl1 = gl[tid * 2 + 1];
        }
        // prefetch next A chunk
        LOAD_A_RAW(an0, an1, more ? (c + 1) * 32 : 0)

        // compute chunk c from LDS buffer nb
        s8v ah, al;
        SPLIT_A(ac0, ac1, ah, al)
#pragma unroll
        for (int j = 0; j < 8; ++j) {
            const s8v whf = *(const s8v*)&lds_h[nb][(j * 64 + lane) * 8];
            const s8v wlf = *(const s8v*)&lds_l[nb][(j * 64 + lane) * 8];
            acc[j] = __builtin_amdgcn_mfma_f32_16x16x32_bf16(ah, whf, acc[j], 0, 0, 0);
            acc[j] = __builtin_amdgcn_mfma_f32_16x16x32_bf16(ah, wlf, acc[j], 0, 0, 0);
            acc[j] = __builtin_amdgcn_mfma_f32_16x16x32_bf16(al, whf, acc[j], 0, 0, 0);
        }

        // write prefetched chunk into the other buffer (read last iter, free now)
        if (more) {
            int4* bh = (int4*)lds_h[fb];
            int4* bl = (int4*)lds_l[fb];
            bh[tid * 2] = nh0;
            bh[tid * 2 + 1] = nh1;
            bl[tid * 2] = nl0;
            bl[tid * 2 + 1] = nl1;
        }
        __syncthreads();
        ac0 = an0; ac1 = an1;
    }

    // C/D layout: col = lane&15, row = quad*4 + reg  (verified m89/m91)
#pragma unroll
    for (int r = 0; r < 4; ++r) {
        const int gr = m0 + quad * 4 + r;
        if (gr >= M) continue;
#pragma unroll
        for (int j = 0; j < 8; ++j) {
            const int col = j * 16 + l16;
            float v = acc[j][r];
            if (bias) v += bias[col];
            if (relu) v = fmaxf(v, 0.f);
            if (Cf) Cf[(long)gr * HBLK + col] = v;
            if (Ch16) Ch16[(long)gr * HBLK + col] = (_Float16)v;
        }
    }
#undef LOAD_A_RAW
#undef SPLIT_A
}

// ---------------- per-node attention-score halves: s_src = z@a[:128], s_dst = z@a[128:] ----------------
__global__ void compute_s(const float* __restrict__ z, const float* __restrict__ a,
                          float* __restrict__ s_src, float* __restrict__ s_dst, int N) {
    const int wave = threadIdx.x >> 6;
    const int lane = threadIdx.x & 63;
    const int n = blockIdx.x * 4 + wave;
    if (n >= N) return;
    const float* zr = z + (long)n * HBLK;
    float v0 = zr[lane], v1 = zr[lane + 64];
    float ss = v0 * a[lane] + v1 * a[lane + 64];
    float sd = v0 * a[128 + lane] + v1 * a[192 + lane];
#pragma unroll
    for (int off = 32; off > 0; off >>= 1) {
        ss += __shfl_down(ss, off);
        sd += __shfl_down(sd, off);
    }
    if (lane == 0) {
        s_src[n] = ss;
        s_dst[n] = sd;
    }
}

// ---------------- per-node softmax stats via perm indirection ----------------
__global__ void node_m(const float* __restrict__ s_src, const float* __restrict__ s_dst,
                       const int* __restrict__ offs, const int* __restrict__ perm,
                       const int* __restrict__ src,
                       float* __restrict__ mb, float* __restrict__ invb, int N) {
    const int wave = threadIdx.x >> 6;
    const int lane = threadIdx.x & 63;
    const int n = blockIdx.x * 4 + wave;
    if (n >= N) return;
    const int beg = offs[n], end = offs[n + 1];
    const float sd = (end > beg) ? s_dst[n] : 0.f;
    float m = -INFINITY, s = 0.f;
    for (int i = beg + lane; i < end; i += 64) {
        float e = sd + s_src[src[perm[i]]];
        e = e > 0.f ? e : 0.01f * e;
        float nm = fmaxf(m, e);
        s = s * __expf(m - nm) + __expf(e - nm);
        m = nm;
    }
#pragma unroll
    for (int off = 32; off > 0; off >>= 1) {
        float m2 = __shfl_down(m, off);
        float s2 = __shfl_down(s, off);
        if (m2 > m) {
            float t = m; m = m2; m2 = t;
            float ts = s; s = s2; s2 = ts;
        }
        s = (m == -INFINITY) ? 0.f : s + s2 * __expf(m2 - m);
    }
    if (lane == 0) {
        mb[n] = m;
        invb[n] = 1.f / fmaxf(s, 1e-16f);
    }
}

// ---------------- per-edge weight + coalesced src_sorted emit ----------------
// Reads perm coalesced, src/dst random (L2-resident, no writeback), writes coalesced.
__global__ void edge_w(const float* __restrict__ s_src, const float* __restrict__ s_dst,
                       const int* __restrict__ src, const int* __restrict__ dst,
                       const int* __restrict__ perm,
                       const float* __restrict__ mb, const float* __restrict__ invb,
                       float* __restrict__ wgt, int* __restrict__ src_sorted, int E) {
    int i = blockIdx.x * 256 + threadIdx.x;
    if (i >= E) return;
    int e = perm[i];
    int s = src[e], d = dst[e];
    float x = s_dst[d] + s_src[s];
    x = x > 0.f ? x : 0.01f * x;
    wgt[i] = __expf(x - mb[d]) * invb[d];
    src_sorted[i] = s;
}

// ---------------- pure weighted gather; one wave per node, fp16 z rows ----------------
__global__ void gat_gather(const float* __restrict__ h_in, const float* __restrict__ hs,
                           const _Float16* __restrict__ zh,
                           const float* __restrict__ wgt,
                           const int* __restrict__ offs, const int* __restrict__ src_sorted,
                           float* __restrict__ h_out, int N) {
    const int wave = threadIdx.x >> 6;
    const int lane = threadIdx.x & 63;
    const int n = blockIdx.x * 4 + wave;
    if (n >= N) return;
    const int g = lane >> 5, l = lane & 31;
    const int beg = offs[n], end = offs[n + 1];

    float4 acc = make_float4(0.f, 0.f, 0.f, 0.f);
    for (int i = beg + g; i < end; i += 2) {
        const float w = wgt[i];
        const int s = src_sorted[i];
        const h4f zv = *(const h4f*)(zh + (long)s * HBLK + 4 * l);
        acc.x += w * (float)zv[0];
        acc.y += w * (float)zv[1];
        acc.z += w * (float)zv[2];
        acc.w += w * (float)zv[3];
    }
    acc.x += __shfl_down(acc.x, 32);
    acc.y += __shfl_down(acc.y, 32);
    acc.z += __shfl_down(acc.z, 32);
    acc.w += __shfl_down(acc.w, 32);

    if (g == 0) {
        const long base = (long)n * HBLK + 4 * l;
        const float4 hi = *(const float4*)(h_in + base);
        float4 v;
        if (end > beg) {
            const float4 hv = *(const float4*)(hs + base);
            v = make_float4(hi.x + hv.x + acc.x, hi.y + hv.y + acc.y,
                            hi.z + hv.z + acc.z, hi.w + hv.w + acc.w);
        } else {  // DGL leaves h at h_in; residual doubles it
            v = make_float4(2.f * hi.x, 2.f * hi.y, 2.f * hi.z, 2.f * hi.w);
        }
        *(float4*)(h_out + base) = v;
    }
}

// ---------------- output projection: out[N x OUT] = h @ W_out^T + b ----------------
__global__ void out_proj(const float* __restrict__ h, const float* __restrict__ W,
                         const float* __restrict__ b, float* __restrict__ out, int OUTD) {
    __shared__ float hr[HBLK];
    const int n = blockIdx.x;
    const int t = threadIdx.x;  // 128
    hr[t] = h[(long)n * HBLK + t];
    __syncthreads();
    if (t < OUTD) {
        float acc = b[t];
        const float* wr = W + t * HBLK;
#pragma unroll 4
        for (int k = 0; k < HBLK; ++k) acc += hr[k] * wr[k];
        out[(long)n * OUTD + t] = acc;
    }
}

extern "C" void kernel_launch(void* const* d_in, const int* in_sizes, int n_in,
                              void* d_out, int out_size, void* d_ws, size_t ws_size,
                              hipStream_t stream) {
    const float* feats = (const float*)d_in[0];
    const float* maps  = (const float*)d_in[2];
    const int* src = (const int*)d_in[4];
    const int* dst = (const int*)d_in[5];
    const float* W_eh  = (const float*)d_in[6];
    const float* b_eh  = (const float*)d_in[7];
    const float* W_cat = (const float*)d_in[10];
    const float* b_cat = (const float*)d_in[11];
    const float* Ws1 = (const float*)d_in[12];
    const float* Wf1 = (const float*)d_in[13];
    const float* a1  = (const float*)d_in[14];
    const float* Ws2 = (const float*)d_in[15];
    const float* Wf2 = (const float*)d_in[16];
    const float* a2  = (const float*)d_in[17];
    const float* W_out = (const float*)d_in[18];
    const float* b_out = (const float*)d_in[19];

    const int N = in_sizes[3];            // snorm_n is (N,1)
    const int E = in_sizes[4];
    const int IN_DIM = in_sizes[0] / N;   // 24
    const int MAPD = in_sizes[2] / N;     // 512
    const int OUTD = in_sizes[19];        // 24
    const int KCAT = MAPD + HBLK;         // 640 (multiple of 32)
    const int KIN_PAD = 32;               // 24 padded to one K-chunk

    // ---- workspace layout ----
    char* p = (char*)d_ws;
    const size_t NH = (size_t)N * HBLK;
    float* hin  = (float*)p;  p += NH * 4;
    float* h0   = (float*)p;  p += NH * 4;
    float* hs   = (float*)p;  p += NH * 4;
    float* zb   = (float*)p;  p += NH * 4;
    float* hout = (float*)p;  p += NH * 4;
    _Float16* zh = (_Float16*)p; p += NH * 2;
    float* ssrc = (float*)p;  p += (size_t)N * 4;
    float* sdst = (float*)p;  p += (size_t)N * 4;
    float* mb   = (float*)p;  p += (size_t)N * 4;
    float* invb = (float*)p;  p += (size_t)N * 4;
    int* counts = (int*)p;    p += (size_t)N * 4;
    int* cursor = (int*)p;    p += (size_t)N * 4;
    int* offs   = (int*)p;    p += (size_t)(N + 1) * 4;
    int* perm   = (int*)p;    p += (size_t)E * 4;
    int* srcs   = (int*)p;    p += (size_t)E * 4;   // src_sorted (coalesced emit)
    float* wgt  = (float*)p;  p += (size_t)E * 4;
    int* bsums  = (int*)p;    p += 256 * 4;
    p = (char*)(((uintptr_t)p + 15) & ~(uintptr_t)15);
    short* Weh_h  = (short*)p; p += (size_t)HBLK * KIN_PAD * 2;
    short* Weh_l  = (short*)p; p += (size_t)HBLK * KIN_PAD * 2;
    short* Wcat_h = (short*)p; p += (size_t)HBLK * KCAT * 2;
    short* Wcat_l = (short*)p; p += (size_t)HBLK * KCAT * 2;
    short* Wly_h[4]; short* Wly_l[4];
    for (int i = 0; i < 4; ++i) {
        Wly_h[i] = (short*)p;  p += (size_t)HBLK * HBLK * 2;
        Wly_l[i] = (short*)p;  p += (size_t)HBLK * HBLK * 2;
    }

    // ---- CSR by dst (rebuilt every call; ws is poisoned between calls) ----
    const int nScanB = (N + 255) / 256;   // <= 256 for N <= 65536
    zero_counts<<<nScanB, 256, 0, stream>>>(counts, N);
    hist_k<<<(E + 255) / 256, 256, 0, stream>>>(dst, counts, E);
    scan1<<<nScanB, 256, 0, stream>>>(counts, offs, bsums, N);
    scan2<<<1, 256, 0, stream>>>(bsums, nScanB);
    scan3<<<nScanB, 256, 0, stream>>>(offs, cursor, bsums, N, E);
    fill_k<<<(E + 255) / 256, 256, 0, stream>>>(dst, cursor, perm, E);

    // ---- weight split+pack (small) ----
    split_w_pack<<<(HBLK * KIN_PAD + 255) / 256, 256, 0, stream>>>(
        W_eh, IN_DIM, IN_DIM, Weh_h, Weh_l, HBLK, KIN_PAD);
    split_w_pack<<<(HBLK * KCAT + 255) / 256, 256, 0, stream>>>(
        W_cat, KCAT, KCAT, Wcat_h, Wcat_l, HBLK, KCAT);
    {
        const float* Wly[4] = {Ws1, Wf1, Ws2, Wf2};
        for (int i = 0; i < 4; ++i)
            split_w_pack<<<(HBLK * HBLK + 255) / 256, 256, 0, stream>>>(
                Wly[i], HBLK, HBLK, Wly_h[i], Wly_l[i], HBLK, HBLK);
    }

    const int gGrid = (N + 63) / 64;
    const int n4 = (N + 3) / 4;
    // ---- front GEMM: h0 = feats @ W_eh^T + b_eh ----
    gemm_mfma<<<dim3(gGrid, 1), 256, 0, stream>>>(
        feats, IN_DIM, IN_DIM, nullptr, 0, IN_DIM, KIN_PAD,
        Weh_h, Weh_l, nullptr, nullptr, b_eh, h0, nullptr, nullptr, N, 0);
    // ---- concat GEMM: hin = relu([maps | h0] @ W_cat^T + b_cat) ----
    gemm_mfma<<<dim3(gGrid, 1), 256, 0, stream>>>(
        maps, MAPD, MAPD, h0, HBLK, KCAT, KCAT,
        Wcat_h, Wcat_l, nullptr, nullptr, b_cat, hin, nullptr, nullptr, N, 1);

    // ---- GAT layer 1: hin -> hout ----
    gemm_mfma<<<dim3(gGrid, 2), 256, 0, stream>>>(
        hin, HBLK, HBLK, nullptr, 0, HBLK, HBLK,
        Wly_h[0], Wly_l[0], Wly_h[1], Wly_l[1], nullptr, hs, zb, zh, N, 0);
    compute_s<<<n4, 256, 0, stream>>>(zb, a1, ssrc, sdst, N);
    node_m<<<n4, 256, 0, stream>>>(ssrc, sdst, offs, perm, src, mb, invb, N);
    edge_w<<<(E + 255) / 256, 256, 0, stream>>>(ssrc, sdst, src, dst, perm, mb, invb, wgt, srcs, E);
    gat_gather<<<n4, 256, 0, stream>>>(hin, hs, zh, wgt, offs, srcs, hout, N);

    // ---- GAT layer 2: hout -> hin ----
    gemm_mfma<<<dim3(gGrid, 2), 256, 0, stream>>>(
        hout, HBLK, HBLK, nullptr, 0, HBLK, HBLK,
        Wly_h[2], Wly_l[2], Wly_h[3], Wly_l[3], nullptr, hs, zb, zh, N, 0);
    compute_s<<<n4, 256, 0, stream>>>(zb, a2, ssrc, sdst, N);
    node_m<<<n4, 256, 0, stream>>>(ssrc, sdst, offs, perm, src, mb, invb, N);
    edge_w<<<(E + 255) / 256, 256, 0, stream>>>(ssrc, sdst, src, dst, perm, mb, invb, wgt, srcs, E);
    gat_gather<<<n4, 256, 0, stream>>>(hout, hs, zh, wgt, offs, srcs, hin, N);

    // ---- output projection ----
    out_proj<<<N, 128, 0, stream>>>(hin, W_out, b_out, (float*)d_out, OUTD);
}

// Round 11
// 383.366 us; speedup vs baseline: 1.1725x; 1.1725x over previous
//
#include <hip/hip_runtime.h>

#define HBLK 128  // hidden width, fixed by problem

typedef __attribute__((ext_vector_type(8))) short s8v;    // 8 bf16 in 4 VGPRs
typedef __attribute__((ext_vector_type(4))) float f32x4;  // MFMA accumulator
typedef __attribute__((ext_vector_type(4))) _Float16 h4f; // 4 fp16 = 8B

// split fp32 into bf16 hi + lo (truncation; residual <= 2^-16 |x|)
__device__ inline void split2(float x, short& h, short& l) {
    unsigned hb = __float_as_uint(x) & 0xFFFF0000u;
    float hf = __uint_as_float(hb);
    float lf = x - hf;
    h = (short)(hb >> 16);
    l = (short)(__float_as_uint(lf) >> 16);
}

__device__ inline void split8(const float4& a0, const float4& a1, s8v& ah, s8v& al) {
    float vv[8];
    *(float4*)&vv[0] = a0;
    *(float4*)&vv[4] = a1;
#pragma unroll
    for (int e = 0; e < 8; ++e) {
        short hh, ll;
        split2(vv[e], hh, ll);
        ah[e] = hh;
        al[e] = ll;
    }
}

// ---------------- CSR build ----------------
__global__ void zero_counts(int* counts, int n) {
    int i = blockIdx.x * 256 + threadIdx.x;
    if (i < n) counts[i] = 0;
}

__global__ void hist_k(const int* __restrict__ dst, int* counts, int E) {
    int e = blockIdx.x * 256 + threadIdx.x;
    if (e < E) atomicAdd(&counts[dst[e]], 1);
}

// ---- parallel exclusive scan, 3 phases (N up to 256*256) ----
__global__ void scan1(const int* __restrict__ counts, int* __restrict__ offs,
                      int* __restrict__ bsums, int n) {
    __shared__ int lds[256];
    const int t = threadIdx.x;
    const int i = blockIdx.x * 256 + t;
    const int v = (i < n) ? counts[i] : 0;
    lds[t] = v;
    __syncthreads();
    for (int off = 1; off < 256; off <<= 1) {
        int add = (t >= off) ? lds[t - off] : 0;
        __syncthreads();
        lds[t] += add;
        __syncthreads();
    }
    if (i < n) offs[i] = lds[t] - v;          // exclusive within block
    if (t == 255) bsums[blockIdx.x] = lds[255];
}

__global__ void scan2(int* __restrict__ bsums, int nb) {
    __shared__ int lds[256];
    const int t = threadIdx.x;
    const int v = (t < nb) ? bsums[t] : 0;
    lds[t] = v;
    __syncthreads();
    for (int off = 1; off < 256; off <<= 1) {
        int add = (t >= off) ? lds[t - off] : 0;
        __syncthreads();
        lds[t] += add;
        __syncthreads();
    }
    if (t < nb) bsums[t] = lds[t] - v;        // exclusive block prefix
}

__global__ void scan3(int* __restrict__ offs, int* __restrict__ cursor,
                      const int* __restrict__ bsums, int n, int E) {
    const int i = blockIdx.x * 256 + threadIdx.x;
    if (i < n) {
        int v = offs[i] + bsums[blockIdx.x];
        offs[i] = v;
        cursor[i] = v;
    }
    if (i == 0) offs[n] = E;                  // total: every edge has a dst
}

// single scattered store carrying the payload: src_sorted[p] = src[e]
__global__ void fill_k(const int* __restrict__ dst, const int* __restrict__ src,
                       int* cursor, int* __restrict__ src_sorted, int E) {
    int e = blockIdx.x * 256 + threadIdx.x;
    if (e < E) {
        int p = atomicAdd(&cursor[dst[e]], 1);
        if (p >= 0 && p < E) src_sorted[p] = src[e];
    }
}

// ---------------- weight split + pack into MFMA-fragment order ----------------
// Chunk-major: off = ((chunk*(C/16) + j)*64 + lane)*8 + t; chunk c of a C-col
// weight occupies a contiguous (C/16)*1024-short block -> stage-able to LDS.
// Pads k >= kin and c >= cin with zeros.
__global__ void split_w_pack(const float* __restrict__ W, int ldw, int kin, int cin,
                             short* __restrict__ dh, short* __restrict__ dl,
                             int C, int K) {
    long i = (long)blockIdx.x * 256 + threadIdx.x;
    if (i >= (long)C * K) return;
    int c = (int)(i / K), k = (int)(i % K);
    float x = (k < kin && c < cin) ? W[(long)c * ldw + k] : 0.f;
    short h, l;
    split2(x, h, l);
    int nj = C >> 4;
    int j = c >> 4, l16 = c & 15;
    int chunk = k >> 5, quad = (k >> 3) & 3, t = k & 7;
    long off = (((long)(chunk * nj + j) * 64) + quad * 16 + l16) * 8 + t;
    dh[off] = h;
    dl[off] = l;
}

// ---------------- split-fp32 MFMA GEMM, LDS-staged W, double-buffered ----------------
__global__ __launch_bounds__(256, 2) void gemm_mfma(
    const float* __restrict__ A1, int lda1, int K1,
    const float* __restrict__ A2, int lda2, int Kin,
    int K,
    const short* __restrict__ W1h, const short* __restrict__ W1l,
    const short* __restrict__ W2h, const short* __restrict__ W2l,
    const float* __restrict__ bias,
    float* __restrict__ C1f, float* __restrict__ C2f,
    _Float16* __restrict__ Czh,
    int M, int relu)
{
    __shared__ short lds_h[2][4096];   // 8 KB per buffer (one 32-k chunk, hi)
    __shared__ short lds_l[2][4096];   // 8 KB per buffer (lo)
    const short* __restrict__ Wh = blockIdx.y ? W2h : W1h;
    const short* __restrict__ Wl = blockIdx.y ? W2l : W1l;
    float* __restrict__ Cf = blockIdx.y ? C2f : C1f;
    _Float16* __restrict__ Ch16 = blockIdx.y ? Czh : nullptr;
    const int tid = threadIdx.x;
    const int wv = tid >> 6;
    const int lane = tid & 63;
    const int l16 = lane & 15;
    const int quad = lane >> 4;
    const int m0 = blockIdx.x * 64 + wv * 16;   // this wave's 16-row tile
    int ra = m0 + l16;
    if (ra >= M) ra = M - 1;                    // clamp loads; stores guarded
    const long r1 = (long)ra * lda1;
    const long r2 = (long)ra * lda2;
    const int NC = K >> 5;                      // 32-k chunks

    f32x4 acc[8];
#pragma unroll
    for (int j = 0; j < 8; ++j) acc[j] = (f32x4){0.f, 0.f, 0.f, 0.f};

#define LOAD_A_RAW(dst0, dst1, kb)                                              \
    {                                                                           \
        const int col0 = (kb) + quad * 8;                                       \
        if (col0 < K1) {                                                        \
            const float* ap = A1 + r1 + col0;                                   \
            dst0 = *(const float4*)ap;                                          \
            dst1 = *(const float4*)(ap + 4);                                    \
        } else if (col0 < Kin) {                                                \
            const float* ap = A2 + r2 + (col0 - K1);                            \
            dst0 = *(const float4*)ap;                                          \
            dst1 = *(const float4*)(ap + 4);                                    \
        } else {                                                                \
            dst0 = make_float4(0.f, 0.f, 0.f, 0.f);                             \
            dst1 = make_float4(0.f, 0.f, 0.f, 0.f);                             \
        }                                                                       \
    }

    // prologue: stage chunk 0 into buffer 0 (8 KB hi + 8 KB lo; 32 B/thread each)
    {
        const int4* gh = (const int4*)Wh;
        const int4* gl = (const int4*)Wl;
        int4* bh = (int4*)lds_h[0];
        int4* bl = (int4*)lds_l[0];
        bh[tid * 2] = gh[tid * 2];
        bh[tid * 2 + 1] = gh[tid * 2 + 1];
        bl[tid * 2] = gl[tid * 2];
        bl[tid * 2 + 1] = gl[tid * 2 + 1];
    }
    float4 ac0, ac1, an0, an1;
    LOAD_A_RAW(ac0, ac1, 0)
    __syncthreads();

    for (int c = 0; c < NC; ++c) {
        const int nb = c & 1, fb = nb ^ 1;
        // prefetch next W chunk global -> regs
        int4 nh0, nh1, nl0, nl1;
        const bool more = (c + 1 < NC);
        if (more) {
            const int4* gh = (const int4*)(Wh + (long)(c + 1) * 4096);
            const int4* gl = (const int4*)(Wl + (long)(c + 1) * 4096);
            nh0 = gh[tid * 2];
            nh1 = gh[tid * 2 + 1];
            nl0 = gl[tid * 2];
            nl1 = gl[tid * 2 + 1];
        }
        // prefetch next A chunk
        LOAD_A_RAW(an0, an1, more ? (c + 1) * 32 : 0)

        // compute chunk c from LDS buffer nb
        s8v ah, al;
        split8(ac0, ac1, ah, al);
#pragma unroll
        for (int j = 0; j < 8; ++j) {
            const s8v whf = *(const s8v*)&lds_h[nb][(j * 64 + lane) * 8];
            const s8v wlf = *(const s8v*)&lds_l[nb][(j * 64 + lane) * 8];
            acc[j] = __builtin_amdgcn_mfma_f32_16x16x32_bf16(ah, whf, acc[j], 0, 0, 0);
            acc[j] = __builtin_amdgcn_mfma_f32_16x16x32_bf16(ah, wlf, acc[j], 0, 0, 0);
            acc[j] = __builtin_amdgcn_mfma_f32_16x16x32_bf16(al, whf, acc[j], 0, 0, 0);
        }

        // write prefetched chunk into the other buffer (read last iter, free now)
        if (more) {
            int4* bh = (int4*)lds_h[fb];
            int4* bl = (int4*)lds_l[fb];
            bh[tid * 2] = nh0;
            bh[tid * 2 + 1] = nh1;
            bl[tid * 2] = nl0;
            bl[tid * 2 + 1] = nl1;
        }
        __syncthreads();
        ac0 = an0; ac1 = an1;
    }

    // C/D layout: col = lane&15, row = quad*4 + reg  (verified m89/m91)
#pragma unroll
    for (int r = 0; r < 4; ++r) {
        const int gr = m0 + quad * 4 + r;
        if (gr >= M) continue;
#pragma unroll
        for (int j = 0; j < 8; ++j) {
            const int col = j * 16 + l16;
            float v = acc[j][r];
            if (bias) v += bias[col];
            if (relu) v = fmaxf(v, 0.f);
            if (Cf) Cf[(long)gr * HBLK + col] = v;
            if (Ch16) Ch16[(long)gr * HBLK + col] = (_Float16)v;
        }
    }
#undef LOAD_A_RAW
}

// ---------------- output projection via MFMA: out[M x OUTD] = A @ Wout^T + b ----------------
// Wout packed with C=32 (2 j-tiles, cols >= OUTD zero), K=128. Whole packed W
// (8 KB hi + 8 KB lo) staged to LDS once. 4 waves x 16 rows = 64 rows/block.
__global__ __launch_bounds__(256) void gemm_out(
    const float* __restrict__ A,
    const short* __restrict__ Wh, const short* __restrict__ Wl,
    const float* __restrict__ bias, float* __restrict__ out,
    int M, int OUTD)
{
    __shared__ short lh[4096], ll[4096];
    const int tid = threadIdx.x;
    if (tid * 2 + 1 < 512) {  // always true for 256 threads; defensive
        const int4* gh = (const int4*)Wh;
        const int4* gl = (const int4*)Wl;
        int4* bh = (int4*)lh;
        int4* bl = (int4*)ll;
        bh[tid * 2] = gh[tid * 2];
        bh[tid * 2 + 1] = gh[tid * 2 + 1];
        bl[tid * 2] = gl[tid * 2];
        bl[tid * 2 + 1] = gl[tid * 2 + 1];
    }
    const int wv = tid >> 6;
    const int lane = tid & 63;
    const int l16 = lane & 15;
    const int quad = lane >> 4;
    const int m0 = blockIdx.x * 64 + wv * 16;
    int ra = m0 + l16;
    if (ra >= M) ra = M - 1;
    const float* arow = A + (long)ra * HBLK + quad * 8;

    f32x4 acc[2];
    acc[0] = (f32x4){0.f, 0.f, 0.f, 0.f};
    acc[1] = (f32x4){0.f, 0.f, 0.f, 0.f};
    __syncthreads();

#pragma unroll
    for (int c = 0; c < 4; ++c) {
        const float4 a0 = *(const float4*)(arow + c * 32);
        const float4 a1 = *(const float4*)(arow + c * 32 + 4);
        s8v ah, al;
        split8(a0, a1, ah, al);
#pragma unroll
        for (int j = 0; j < 2; ++j) {
            const s8v whf = *(const s8v*)&lh[((c * 2 + j) * 64 + lane) * 8];
            const s8v wlf = *(const s8v*)&ll[((c * 2 + j) * 64 + lane) * 8];
            acc[j] = __builtin_amdgcn_mfma_f32_16x16x32_bf16(ah, whf, acc[j], 0, 0, 0);
            acc[j] = __builtin_amdgcn_mfma_f32_16x16x32_bf16(ah, wlf, acc[j], 0, 0, 0);
            acc[j] = __builtin_amdgcn_mfma_f32_16x16x32_bf16(al, whf, acc[j], 0, 0, 0);
        }
    }

#pragma unroll
    for (int r = 0; r < 4; ++r) {
        const int gr = m0 + quad * 4 + r;
        if (gr >= M) continue;
#pragma unroll
        for (int j = 0; j < 2; ++j) {
            const int col = j * 16 + l16;
            if (col < OUTD)
                out[(long)gr * OUTD + col] = acc[j][r] + bias[col];
        }
    }
}

// ---------------- per-node attention-score halves: s_src = z@a[:128], s_dst = z@a[128:] ----------------
__global__ void compute_s(const float* __restrict__ z, const float* __restrict__ a,
                          float* __restrict__ s_src, float* __restrict__ s_dst, int N) {
    const int wave = threadIdx.x >> 6;
    const int lane = threadIdx.x & 63;
    const int n = blockIdx.x * 4 + wave;
    if (n >= N) return;
    const float* zr = z + (long)n * HBLK;
    float v0 = zr[lane], v1 = zr[lane + 64];
    float ss = v0 * a[lane] + v1 * a[lane + 64];
    float sd = v0 * a[128 + lane] + v1 * a[192 + lane];
#pragma unroll
    for (int off = 32; off > 0; off >>= 1) {
        ss += __shfl_down(ss, off);
        sd += __shfl_down(sd, off);
    }
    if (lane == 0) {
        s_src[n] = ss;
        s_dst[n] = sd;
    }
}

// ---------------- per-node softmax stats + edge weights (one wave per node) ----------------
// pass 1: online max/sum over the node's edges; pass 2: write wgt[i] coalesced
// within the node's CSR range.
__global__ void node_mw(const float* __restrict__ s_src, const float* __restrict__ s_dst,
                        const int* __restrict__ offs, const int* __restrict__ srcs,
                        float* __restrict__ wgt, int N) {
    const int wave = threadIdx.x >> 6;
    const int lane = threadIdx.x & 63;
    const int n = blockIdx.x * 4 + wave;
    if (n >= N) return;
    const int beg = offs[n], end = offs[n + 1];
    if (end <= beg) return;
    const float sd = s_dst[n];
    float m = -INFINITY, s = 0.f;
    for (int i = beg + lane; i < end; i += 64) {
        float e = sd + s_src[srcs[i]];
        e = e > 0.f ? e : 0.01f * e;
        float nm = fmaxf(m, e);
        s = s * __expf(m - nm) + __expf(e - nm);
        m = nm;
    }
#pragma unroll
    for (int off = 32; off > 0; off >>= 1) {
        float m2 = __shfl_down(m, off);
        float s2 = __shfl_down(s, off);
        if (m2 > m) {
            float t = m; m = m2; m2 = t;
            float ts = s; s = s2; s2 = ts;
        }
        s = (m == -INFINITY) ? 0.f : s + s2 * __expf(m2 - m);
    }
    m = __shfl(m, 0);
    s = __shfl(s, 0);
    const float inv = 1.f / fmaxf(s, 1e-16f);
    for (int i = beg + lane; i < end; i += 64) {
        float e = sd + s_src[srcs[i]];
        e = e > 0.f ? e : 0.01f * e;
        wgt[i] = __expf(e - m) * inv;
    }
}

// ---------------- pure weighted gather; one wave per node, fp16 z rows ----------------
__global__ void gat_gather(const float* __restrict__ h_in, const float* __restrict__ hs,
                           const _Float16* __restrict__ zh,
                           const float* __restrict__ wgt,
                           const int* __restrict__ offs, const int* __restrict__ src_sorted,
                           float* __restrict__ h_out, int N) {
    const int wave = threadIdx.x >> 6;
    const int lane = threadIdx.x & 63;
    const int n = blockIdx.x * 4 + wave;
    if (n >= N) return;
    const int g = lane >> 5, l = lane & 31;
    const int beg = offs[n], end = offs[n + 1];

    float4 acc = make_float4(0.f, 0.f, 0.f, 0.f);
    for (int i = beg + g; i < end; i += 2) {
        const float w = wgt[i];
        const int s = src_sorted[i];
        const h4f zv = *(const h4f*)(zh + (long)s * HBLK + 4 * l);
        acc.x += w * (float)zv[0];
        acc.y += w * (float)zv[1];
        acc.z += w * (float)zv[2];
        acc.w += w * (float)zv[3];
    }
    acc.x += __shfl_down(acc.x, 32);
    acc.y += __shfl_down(acc.y, 32);
    acc.z += __shfl_down(acc.z, 32);
    acc.w += __shfl_down(acc.w, 32);

    if (g == 0) {
        const long base = (long)n * HBLK + 4 * l;
        const float4 hi = *(const float4*)(h_in + base);
        float4 v;
        if (end > beg) {
            const float4 hv = *(const float4*)(hs + base);
            v = make_float4(hi.x + hv.x + acc.x, hi.y + hv.y + acc.y,
                            hi.z + hv.z + acc.z, hi.w + hv.w + acc.w);
        } else {  // DGL leaves h at h_in; residual doubles it
            v = make_float4(2.f * hi.x, 2.f * hi.y, 2.f * hi.z, 2.f * hi.w);
        }
        *(float4*)(h_out + base) = v;
    }
}

extern "C" void kernel_launch(void* const* d_in, const int* in_sizes, int n_in,
                              void* d_out, int out_size, void* d_ws, size_t ws_size,
                              hipStream_t stream) {
    const float* feats = (const float*)d_in[0];
    const float* maps  = (const float*)d_in[2];
    const int* src = (const int*)d_in[4];
    const int* dst = (const int*)d_in[5];
    const float* W_eh  = (const float*)d_in[6];
    const float* b_eh  = (const float*)d_in[7];
    const float* W_cat = (const float*)d_in[10];
    const float* b_cat = (const float*)d_in[11];
    const float* Ws1 = (const float*)d_in[12];
    const float* Wf1 = (const float*)d_in[13];
    const float* a1  = (const float*)d_in[14];
    const float* Ws2 = (const float*)d_in[15];
    const float* Wf2 = (const float*)d_in[16];
    const float* a2  = (const float*)d_in[17];
    const float* W_out = (const float*)d_in[18];
    const float* b_out = (const float*)d_in[19];

    const int N = in_sizes[3];            // snorm_n is (N,1)
    const int E = in_sizes[4];
    const int IN_DIM = in_sizes[0] / N;   // 24
    const int MAPD = in_sizes[2] / N;     // 512
    const int OUTD = in_sizes[19];        // 24
    const int KCAT = MAPD + HBLK;         // 640 (multiple of 32)
    const int KIN_PAD = 32;               // 24 padded to one K-chunk

    // ---- workspace layout ----
    char* p = (char*)d_ws;
    const size_t NH = (size_t)N * HBLK;
    float* hin  = (float*)p;  p += NH * 4;
    float* h0   = (float*)p;  p += NH * 4;
    float* hs   = (float*)p;  p += NH * 4;
    float* zb   = (float*)p;  p += NH * 4;
    float* hout = (float*)p;  p += NH * 4;
    _Float16* zh = (_Float16*)p; p += NH * 2;
    float* ssrc = (float*)p;  p += (size_t)N * 4;
    float* sdst = (float*)p;  p += (size_t)N * 4;
    int* counts = (int*)p;    p += (size_t)N * 4;
    int* cursor = (int*)p;    p += (size_t)N * 4;
    int* offs   = (int*)p;    p += (size_t)(N + 1) * 4;
    int* srcs   = (int*)p;    p += (size_t)E * 4;   // src payload, dst-sorted
    float* wgt  = (float*)p;  p += (size_t)E * 4;
    int* bsums  = (int*)p;    p += 256 * 4;
    p = (char*)(((uintptr_t)p + 15) & ~(uintptr_t)15);
    short* Weh_h  = (short*)p; p += (size_t)HBLK * KIN_PAD * 2;
    short* Weh_l  = (short*)p; p += (size_t)HBLK * KIN_PAD * 2;
    short* Wcat_h = (short*)p; p += (size_t)HBLK * KCAT * 2;
    short* Wcat_l = (short*)p; p += (size_t)HBLK * KCAT * 2;
    short* Wout_h = (short*)p; p += (size_t)32 * HBLK * 2;
    short* Wout_l = (short*)p; p += (size_t)32 * HBLK * 2;
    short* Wly_h[4]; short* Wly_l[4];
    for (int i = 0; i < 4; ++i) {
        Wly_h[i] = (short*)p;  p += (size_t)HBLK * HBLK * 2;
        Wly_l[i] = (short*)p;  p += (size_t)HBLK * HBLK * 2;
    }

    // ---- CSR by dst (rebuilt every call; ws is poisoned between calls) ----
    const int nScanB = (N + 255) / 256;   // <= 256 for N <= 65536
    zero_counts<<<nScanB, 256, 0, stream>>>(counts, N);
    hist_k<<<(E + 255) / 256, 256, 0, stream>>>(dst, counts, E);
    scan1<<<nScanB, 256, 0, stream>>>(counts, offs, bsums, N);
    scan2<<<1, 256, 0, stream>>>(bsums, nScanB);
    scan3<<<nScanB, 256, 0, stream>>>(offs, cursor, bsums, N, E);
    fill_k<<<(E + 255) / 256, 256, 0, stream>>>(dst, src, cursor, srcs, E);

    // ---- weight split+pack (small) ----
    split_w_pack<<<(HBLK * KIN_PAD + 255) / 256, 256, 0, stream>>>(
        W_eh, IN_DIM, IN_DIM, HBLK, Weh_h, Weh_l, HBLK, KIN_PAD);
    split_w_pack<<<(HBLK * KCAT + 255) / 256, 256, 0, stream>>>(
        W_cat, KCAT, KCAT, HBLK, Wcat_h, Wcat_l, HBLK, KCAT);
    split_w_pack<<<(32 * HBLK + 255) / 256, 256, 0, stream>>>(
        W_out, HBLK, HBLK, OUTD, Wout_h, Wout_l, 32, HBLK);
    {
        const float* Wly[4] = {Ws1, Wf1, Ws2, Wf2};
        for (int i = 0; i < 4; ++i)
            split_w_pack<<<(HBLK * HBLK + 255) / 256, 256, 0, stream>>>(
                Wly[i], HBLK, HBLK, HBLK, Wly_h[i], Wly_l[i], HBLK, HBLK);
    }

    const int gGrid = (N + 63) / 64;
    const int n4 = (N + 3) / 4;
    // ---- front GEMM: h0 = feats @ W_eh^T + b_eh ----
    gemm_mfma<<<dim3(gGrid, 1), 256, 0, stream>>>(
        feats, IN_DIM, IN_DIM, nullptr, 0, IN_DIM, KIN_PAD,
        Weh_h, Weh_l, nullptr, nullptr, b_eh, h0, nullptr, nullptr, N, 0);
    // ---- concat GEMM: hin = relu([maps | h0] @ W_cat^T + b_cat) ----
    gemm_mfma<<<dim3(gGrid, 1), 256, 0, stream>>>(
        maps, MAPD, MAPD, h0, HBLK, KCAT, KCAT,
        Wcat_h, Wcat_l, nullptr, nullptr, b_cat, hin, nullptr, nullptr, N, 1);

    // ---- GAT layer 1: hin -> hout ----
    gemm_mfma<<<dim3(gGrid, 2), 256, 0, stream>>>(
        hin, HBLK, HBLK, nullptr, 0, HBLK, HBLK,
        Wly_h[0], Wly_l[0], Wly_h[1], Wly_l[1], nullptr, hs, zb, zh, N, 0);
    compute_s<<<n4, 256, 0, stream>>>(zb, a1, ssrc, sdst, N);
    node_mw<<<n4, 256, 0, stream>>>(ssrc, sdst, offs, srcs, wgt, N);
    gat_gather<<<n4, 256, 0, stream>>>(hin, hs, zh, wgt, offs, srcs, hout, N);

    // ---- GAT layer 2: hout -> hin ----
    gemm_mfma<<<dim3(gGrid, 2), 256, 0, stream>>>(
        hout, HBLK, HBLK, nullptr, 0, HBLK, HBLK,
        Wly_h[2], Wly_l[2], Wly_h[3], Wly_l[3], nullptr, hs, zb, zh, N, 0);
    compute_s<<<n4, 256, 0, stream>>>(zb, a2, ssrc, sdst, N);
    node_mw<<<n4, 256, 0, stream>>>(ssrc, sdst, offs, srcs, wgt, N);
    gat_gather<<<n4, 256, 0, stream>>>(hout, hs, zh, wgt, offs, srcs, hin, N);

    // ---- output projection (MFMA) ----
    gemm_out<<<gGrid, 256, 0, stream>>>(hin, Wout_h, Wout_l, b_out, (float*)d_out, N, OUTD);
}

// Round 12
// 345.517 us; speedup vs baseline: 1.3009x; 1.1095x over previous
//
#include <hip/hip_runtime.h>

#define HBLK 128  // hidden width, fixed by problem

typedef __attribute__((ext_vector_type(8))) short s8v;    // 8 bf16 in 4 VGPRs
typedef __attribute__((ext_vector_type(4))) float f32x4;  // MFMA accumulator
typedef __attribute__((ext_vector_type(8))) _Float16 h8f; // 8 fp16 = 16B

// split fp32 into bf16 hi + lo (truncation; residual <= 2^-16 |x|)
__device__ inline void split2(float x, short& h, short& l) {
    unsigned hb = __float_as_uint(x) & 0xFFFF0000u;
    float hf = __uint_as_float(hb);
    float lf = x - hf;
    h = (short)(hb >> 16);
    l = (short)(__float_as_uint(lf) >> 16);
}

__device__ inline void split8(const float4& a0, const float4& a1, s8v& ah, s8v& al) {
    float vv[8];
    *(float4*)&vv[0] = a0;
    *(float4*)&vv[4] = a1;
#pragma unroll
    for (int e = 0; e < 8; ++e) {
        short hh, ll;
        split2(vv[e], hh, ll);
        ah[e] = hh;
        al[e] = ll;
    }
}

// ---------------- CSR build ----------------
__global__ void zero_counts(int* counts, int n) {
    int i = blockIdx.x * 256 + threadIdx.x;
    if (i < n) counts[i] = 0;
}

__global__ void hist_k(const int* __restrict__ dst, int* counts, int E) {
    int e = blockIdx.x * 256 + threadIdx.x;
    if (e < E) atomicAdd(&counts[dst[e]], 1);
}

// ---- parallel exclusive scan, 3 phases (N up to 256*256) ----
__global__ void scan1(const int* __restrict__ counts, int* __restrict__ offs,
                      int* __restrict__ bsums, int n) {
    __shared__ int lds[256];
    const int t = threadIdx.x;
    const int i = blockIdx.x * 256 + t;
    const int v = (i < n) ? counts[i] : 0;
    lds[t] = v;
    __syncthreads();
    for (int off = 1; off < 256; off <<= 1) {
        int add = (t >= off) ? lds[t - off] : 0;
        __syncthreads();
        lds[t] += add;
        __syncthreads();
    }
    if (i < n) offs[i] = lds[t] - v;          // exclusive within block
    if (t == 255) bsums[blockIdx.x] = lds[255];
}

__global__ void scan2(int* __restrict__ bsums, int nb) {
    __shared__ int lds[256];
    const int t = threadIdx.x;
    const int v = (t < nb) ? bsums[t] : 0;
    lds[t] = v;
    __syncthreads();
    for (int off = 1; off < 256; off <<= 1) {
        int add = (t >= off) ? lds[t - off] : 0;
        __syncthreads();
        lds[t] += add;
        __syncthreads();
    }
    if (t < nb) bsums[t] = lds[t] - v;        // exclusive block prefix
}

__global__ void scan3(int* __restrict__ offs, int* __restrict__ cursor,
                      const int* __restrict__ bsums, int n, int E) {
    const int i = blockIdx.x * 256 + threadIdx.x;
    if (i < n) {
        int v = offs[i] + bsums[blockIdx.x];
        offs[i] = v;
        cursor[i] = v;
    }
    if (i == 0) offs[n] = E;                  // total: every edge has a dst
}

// single scattered store carrying the payload: src_sorted[p] = src[e]
__global__ void fill_k(const int* __restrict__ dst, const int* __restrict__ src,
                       int* cursor, int* __restrict__ src_sorted, int E) {
    int e = blockIdx.x * 256 + threadIdx.x;
    if (e < E) {
        int p = atomicAdd(&cursor[dst[e]], 1);
        if (p >= 0 && p < E) src_sorted[p] = src[e];
    }
}

// ---------------- weight split + pack into MFMA-fragment order ----------------
// Chunk-major: off = ((chunk*(C/16) + j)*64 + lane)*8 + t; chunk c of a C-col
// weight occupies a contiguous (C/16)*1024-short block -> stage-able to LDS.
// Pads k >= kin and c >= cin with zeros.
__global__ void split_w_pack(const float* __restrict__ W, int ldw, int kin, int cin,
                             short* __restrict__ dh, short* __restrict__ dl,
                             int C, int K) {
    long i = (long)blockIdx.x * 256 + threadIdx.x;
    if (i >= (long)C * K) return;
    int c = (int)(i / K), k = (int)(i % K);
    float x = (k < kin && c < cin) ? W[(long)c * ldw + k] : 0.f;
    short h, l;
    split2(x, h, l);
    int nj = C >> 4;
    int j = c >> 4, l16 = c & 15;
    int chunk = k >> 5, quad = (k >> 3) & 3, t = k & 7;
    long off = (((long)(chunk * nj + j) * 64) + quad * 16 + l16) * 8 + t;
    dh[off] = h;
    dl[off] = l;
}

// ---------------- split-fp32 MFMA GEMM, LDS-staged W, double-buffered ----------------
__global__ __launch_bounds__(256, 2) void gemm_mfma(
    const float* __restrict__ A1, int lda1, int K1,
    const float* __restrict__ A2, int lda2, int Kin,
    int K,
    const short* __restrict__ W1h, const short* __restrict__ W1l,
    const short* __restrict__ W2h, const short* __restrict__ W2l,
    const float* __restrict__ bias,
    float* __restrict__ C1f, float* __restrict__ C2f,
    _Float16* __restrict__ Czh,
    int M, int relu)
{
    __shared__ short lds_h[2][4096];   // 8 KB per buffer (one 32-k chunk, hi)
    __shared__ short lds_l[2][4096];   // 8 KB per buffer (lo)
    const short* __restrict__ Wh = blockIdx.y ? W2h : W1h;
    const short* __restrict__ Wl = blockIdx.y ? W2l : W1l;
    float* __restrict__ Cf = blockIdx.y ? C2f : C1f;
    _Float16* __restrict__ Ch16 = blockIdx.y ? Czh : nullptr;
    const int tid = threadIdx.x;
    const int wv = tid >> 6;
    const int lane = tid & 63;
    const int l16 = lane & 15;
    const int quad = lane >> 4;
    const int m0 = blockIdx.x * 64 + wv * 16;   // this wave's 16-row tile
    int ra = m0 + l16;
    if (ra >= M) ra = M - 1;                    // clamp loads; stores guarded
    const long r1 = (long)ra * lda1;
    const long r2 = (long)ra * lda2;
    const int NC = K >> 5;                      // 32-k chunks

    f32x4 acc[8];
#pragma unroll
    for (int j = 0; j < 8; ++j) acc[j] = (f32x4){0.f, 0.f, 0.f, 0.f};

#define LOAD_A_RAW(dst0, dst1, kb)                                              \
    {                                                                           \
        const int col0 = (kb) + quad * 8;                                       \
        if (col0 < K1) {                                                        \
            const float* ap = A1 + r1 + col0;                                   \
            dst0 = *(const float4*)ap;                                          \
            dst1 = *(const float4*)(ap + 4);                                    \
        } else if (col0 < Kin) {                                                \
            const float* ap = A2 + r2 + (col0 - K1);                            \
            dst0 = *(const float4*)ap;                                          \
            dst1 = *(const float4*)(ap + 4);                                    \
        } else {                                                                \
            dst0 = make_float4(0.f, 0.f, 0.f, 0.f);                             \
            dst1 = make_float4(0.f, 0.f, 0.f, 0.f);                             \
        }                                                                       \
    }

    // prologue: stage chunk 0 into buffer 0 (8 KB hi + 8 KB lo; 32 B/thread each)
    {
        const int4* gh = (const int4*)Wh;
        const int4* gl = (const int4*)Wl;
        int4* bh = (int4*)lds_h[0];
        int4* bl = (int4*)lds_l[0];
        bh[tid * 2] = gh[tid * 2];
        bh[tid * 2 + 1] = gh[tid * 2 + 1];
        bl[tid * 2] = gl[tid * 2];
        bl[tid * 2 + 1] = gl[tid * 2 + 1];
    }
    float4 ac0, ac1, an0, an1;
    LOAD_A_RAW(ac0, ac1, 0)
    __syncthreads();

    for (int c = 0; c < NC; ++c) {
        const int nb = c & 1, fb = nb ^ 1;
        // prefetch next W chunk global -> regs
        int4 nh0, nh1, nl0, nl1;
        const bool more = (c + 1 < NC);
        if (more) {
            const int4* gh = (const int4*)(Wh + (long)(c + 1) * 4096);
            const int4* gl = (const int4*)(Wl + (long)(c + 1) * 4096);
            nh0 = gh[tid * 2];
            nh1 = gh[tid * 2 + 1];
            nl0 = gl[tid * 2];
            nl1 = gl[tid * 2 + 1];
        }
        // prefetch next A chunk
        LOAD_A_RAW(an0, an1, more ? (c + 1) * 32 : 0)

        // compute chunk c from LDS buffer nb
        s8v ah, al;
        split8(ac0, ac1, ah, al);
#pragma unroll
        for (int j = 0; j < 8; ++j) {
            const s8v whf = *(const s8v*)&lds_h[nb][(j * 64 + lane) * 8];
            const s8v wlf = *(const s8v*)&lds_l[nb][(j * 64 + lane) * 8];
            acc[j] = __builtin_amdgcn_mfma_f32_16x16x32_bf16(ah, whf, acc[j], 0, 0, 0);
            acc[j] = __builtin_amdgcn_mfma_f32_16x16x32_bf16(ah, wlf, acc[j], 0, 0, 0);
            acc[j] = __builtin_amdgcn_mfma_f32_16x16x32_bf16(al, whf, acc[j], 0, 0, 0);
        }

        // write prefetched chunk into the other buffer (read last iter, free now)
        if (more) {
            int4* bh = (int4*)lds_h[fb];
            int4* bl = (int4*)lds_l[fb];
            bh[tid * 2] = nh0;
            bh[tid * 2 + 1] = nh1;
            bl[tid * 2] = nl0;
            bl[tid * 2 + 1] = nl1;
        }
        __syncthreads();
        ac0 = an0; ac1 = an1;
    }

    // C/D layout: col = lane&15, row = quad*4 + reg  (verified m89/m91)
#pragma unroll
    for (int r = 0; r < 4; ++r) {
        const int gr = m0 + quad * 4 + r;
        if (gr >= M) continue;
#pragma unroll
        for (int j = 0; j < 8; ++j) {
            const int col = j * 16 + l16;
            float v = acc[j][r];
            if (bias) v += bias[col];
            if (relu) v = fmaxf(v, 0.f);
            if (Cf) Cf[(long)gr * HBLK + col] = v;
            if (Ch16) Ch16[(long)gr * HBLK + col] = (_Float16)v;
        }
    }
#undef LOAD_A_RAW
}

// ---------------- output projection via MFMA: out[M x OUTD] = A @ Wout^T + b ----------------
__global__ __launch_bounds__(256) void gemm_out(
    const float* __restrict__ A,
    const short* __restrict__ Wh, const short* __restrict__ Wl,
    const float* __restrict__ bias, float* __restrict__ out,
    int M, int OUTD)
{
    __shared__ short lh[4096], ll[4096];
    const int tid = threadIdx.x;
    {
        const int4* gh = (const int4*)Wh;
        const int4* gl = (const int4*)Wl;
        int4* bh = (int4*)lh;
        int4* bl = (int4*)ll;
        bh[tid * 2] = gh[tid * 2];
        bh[tid * 2 + 1] = gh[tid * 2 + 1];
        bl[tid * 2] = gl[tid * 2];
        bl[tid * 2 + 1] = gl[tid * 2 + 1];
    }
    const int wv = tid >> 6;
    const int lane = tid & 63;
    const int l16 = lane & 15;
    const int quad = lane >> 4;
    const int m0 = blockIdx.x * 64 + wv * 16;
    int ra = m0 + l16;
    if (ra >= M) ra = M - 1;
    const float* arow = A + (long)ra * HBLK + quad * 8;

    f32x4 acc[2];
    acc[0] = (f32x4){0.f, 0.f, 0.f, 0.f};
    acc[1] = (f32x4){0.f, 0.f, 0.f, 0.f};
    __syncthreads();

#pragma unroll
    for (int c = 0; c < 4; ++c) {
        const float4 a0 = *(const float4*)(arow + c * 32);
        const float4 a1 = *(const float4*)(arow + c * 32 + 4);
        s8v ah, al;
        split8(a0, a1, ah, al);
#pragma unroll
        for (int j = 0; j < 2; ++j) {
            const s8v whf = *(const s8v*)&lh[((c * 2 + j) * 64 + lane) * 8];
            const s8v wlf = *(const s8v*)&ll[((c * 2 + j) * 64 + lane) * 8];
            acc[j] = __builtin_amdgcn_mfma_f32_16x16x32_bf16(ah, whf, acc[j], 0, 0, 0);
            acc[j] = __builtin_amdgcn_mfma_f32_16x16x32_bf16(ah, wlf, acc[j], 0, 0, 0);
            acc[j] = __builtin_amdgcn_mfma_f32_16x16x32_bf16(al, whf, acc[j], 0, 0, 0);
        }
    }

#pragma unroll
    for (int r = 0; r < 4; ++r) {
        const int gr = m0 + quad * 4 + r;
        if (gr >= M) continue;
#pragma unroll
        for (int j = 0; j < 2; ++j) {
            const int col = j * 16 + l16;
            if (col < OUTD)
                out[(long)gr * OUTD + col] = acc[j][r] + bias[col];
        }
    }
}

// ---------------- per-node attention-score halves: s_src = z@a[:128], s_dst = z@a[128:] ----------------
__global__ void compute_s(const float* __restrict__ z, const float* __restrict__ a,
                          float* __restrict__ s_src, float* __restrict__ s_dst, int N) {
    const int wave = threadIdx.x >> 6;
    const int lane = threadIdx.x & 63;
    const int n = blockIdx.x * 4 + wave;
    if (n >= N) return;
    const float* zr = z + (long)n * HBLK;
    float v0 = zr[lane], v1 = zr[lane + 64];
    float ss = v0 * a[lane] + v1 * a[lane + 64];
    float sd = v0 * a[128 + lane] + v1 * a[192 + lane];
#pragma unroll
    for (int off = 32; off > 0; off >>= 1) {
        ss += __shfl_down(ss, off);
        sd += __shfl_down(sd, off);
    }
    if (lane == 0) {
        s_src[n] = ss;
        s_dst[n] = sd;
    }
}

// ---------------- per-node softmax stats + edge weights (one wave per node) ----------------
__global__ void node_mw(const float* __restrict__ s_src, const float* __restrict__ s_dst,
                        const int* __restrict__ offs, const int* __restrict__ srcs,
                        float* __restrict__ wgt, int N) {
    const int wave = threadIdx.x >> 6;
    const int lane = threadIdx.x & 63;
    const int n = blockIdx.x * 4 + wave;
    if (n >= N) return;
    const int beg = offs[n], end = offs[n + 1];
    if (end <= beg) return;
    const float sd = s_dst[n];
    float m = -INFINITY, s = 0.f;
    for (int i = beg + lane; i < end; i += 64) {
        float e = sd + s_src[srcs[i]];
        e = e > 0.f ? e : 0.01f * e;
        float nm = fmaxf(m, e);
        s = s * __expf(m - nm) + __expf(e - nm);
        m = nm;
    }
#pragma unroll
    for (int off = 32; off > 0; off >>= 1) {
        float m2 = __shfl_down(m, off);
        float s2 = __shfl_down(s, off);
        if (m2 > m) {
            float t = m; m = m2; m2 = t;
            float ts = s; s = s2; s2 = ts;
        }
        s = (m == -INFINITY) ? 0.f : s + s2 * __expf(m2 - m);
    }
    m = __shfl(m, 0);
    s = __shfl(s, 0);
    const float inv = 1.f / fmaxf(s, 1e-16f);
    for (int i = beg + lane; i < end; i += 64) {
        float e = sd + s_src[srcs[i]];
        e = e > 0.f ? e : 0.01f * e;
        wgt[i] = __expf(e - m) * inv;
    }
}

// ---------------- pure weighted gather; one wave per node, fp16 z rows ----------------
// 4 groups of 16 lanes; lane owns cols [8l, 8l+7] (16B loads); group g handles
// edges beg+g, beg+g+4, ... with 2-way unroll -> up to 8 outstanding gathers/wave.
__global__ void gat_gather(const float* __restrict__ h_in, const float* __restrict__ hs,
                           const _Float16* __restrict__ zh,
                           const float* __restrict__ wgt,
                           const int* __restrict__ offs, const int* __restrict__ src_sorted,
                           float* __restrict__ h_out, int N) {
    const int wave = threadIdx.x >> 6;
    const int lane = threadIdx.x & 63;
    const int n = blockIdx.x * 4 + wave;
    if (n >= N) return;
    const int g = lane >> 4, l = lane & 15;
    const int beg = offs[n], end = offs[n + 1];

    float acc[8] = {};
    int i = beg + g;
    for (; i + 4 < end; i += 8) {
        const int s0 = src_sorted[i];
        const int s1 = src_sorted[i + 4];
        const float w0 = wgt[i];
        const float w1 = wgt[i + 4];
        const h8f z0 = *(const h8f*)(zh + (long)s0 * HBLK + 8 * l);
        const h8f z1 = *(const h8f*)(zh + (long)s1 * HBLK + 8 * l);
#pragma unroll
        for (int e = 0; e < 8; ++e)
            acc[e] += w0 * (float)z0[e] + w1 * (float)z1[e];
    }
    if (i < end) {
        const int s0 = src_sorted[i];
        const float w0 = wgt[i];
        const h8f z0 = *(const h8f*)(zh + (long)s0 * HBLK + 8 * l);
#pragma unroll
        for (int e = 0; e < 8; ++e)
            acc[e] += w0 * (float)z0[e];
    }
    // combine the 4 groups (all own the same col mapping)
#pragma unroll
    for (int e = 0; e < 8; ++e) {
        acc[e] += __shfl_down(acc[e], 32);
        acc[e] += __shfl_down(acc[e], 16);
    }

    if (g == 0) {
        const long base = (long)n * HBLK + 8 * l;
        const float4 hi0 = *(const float4*)(h_in + base);
        const float4 hi1 = *(const float4*)(h_in + base + 4);
        float o[8];
        if (end > beg) {
            const float4 hv0 = *(const float4*)(hs + base);
            const float4 hv1 = *(const float4*)(hs + base + 4);
            const float* hip = (const float*)&hi0;
            const float* hvp = (const float*)&hv0;
#pragma unroll
            for (int e = 0; e < 4; ++e) o[e] = hip[e] + hvp[e] + acc[e];
            const float* hip1 = (const float*)&hi1;
            const float* hvp1 = (const float*)&hv1;
#pragma unroll
            for (int e = 0; e < 4; ++e) o[4 + e] = hip1[e] + hvp1[e] + acc[4 + e];
        } else {  // DGL leaves h at h_in; residual doubles it
            const float* hip = (const float*)&hi0;
            const float* hip1 = (const float*)&hi1;
#pragma unroll
            for (int e = 0; e < 4; ++e) o[e] = 2.f * hip[e];
#pragma unroll
            for (int e = 0; e < 4; ++e) o[4 + e] = 2.f * hip1[e];
        }
        *(float4*)(h_out + base) = *(float4*)&o[0];
        *(float4*)(h_out + base + 4) = *(float4*)&o[4];
    }
}

extern "C" void kernel_launch(void* const* d_in, const int* in_sizes, int n_in,
                              void* d_out, int out_size, void* d_ws, size_t ws_size,
                              hipStream_t stream) {
    const float* feats = (const float*)d_in[0];
    const float* maps  = (const float*)d_in[2];
    const int* src = (const int*)d_in[4];
    const int* dst = (const int*)d_in[5];
    const float* W_eh  = (const float*)d_in[6];
    const float* b_eh  = (const float*)d_in[7];
    const float* W_cat = (const float*)d_in[10];
    const float* b_cat = (const float*)d_in[11];
    const float* Ws1 = (const float*)d_in[12];
    const float* Wf1 = (const float*)d_in[13];
    const float* a1  = (const float*)d_in[14];
    const float* Ws2 = (const float*)d_in[15];
    const float* Wf2 = (const float*)d_in[16];
    const float* a2  = (const float*)d_in[17];
    const float* W_out = (const float*)d_in[18];
    const float* b_out = (const float*)d_in[19];

    const int N = in_sizes[3];            // snorm_n is (N,1)
    const int E = in_sizes[4];
    const int IN_DIM = in_sizes[0] / N;   // 24
    const int MAPD = in_sizes[2] / N;     // 512
    const int OUTD = in_sizes[19];        // 24
    const int KCAT = MAPD + HBLK;         // 640 (multiple of 32)
    const int KIN_PAD = 32;               // 24 padded to one K-chunk

    // ---- workspace layout ----
    char* p = (char*)d_ws;
    const size_t NH = (size_t)N * HBLK;
    float* hin  = (float*)p;  p += NH * 4;
    float* h0   = (float*)p;  p += NH * 4;
    float* hs   = (float*)p;  p += NH * 4;
    float* zb   = (float*)p;  p += NH * 4;
    float* hout = (float*)p;  p += NH * 4;
    _Float16* zh = (_Float16*)p; p += NH * 2;
    float* ssrc = (float*)p;  p += (size_t)N * 4;
    float* sdst = (float*)p;  p += (size_t)N * 4;
    int* counts = (int*)p;    p += (size_t)N * 4;
    int* cursor = (int*)p;    p += (size_t)N * 4;
    int* offs   = (int*)p;    p += (size_t)(N + 1) * 4;
    int* srcs   = (int*)p;    p += (size_t)E * 4;   // src payload, dst-sorted
    float* wgt  = (float*)p;  p += (size_t)E * 4;
    int* bsums  = (int*)p;    p += 256 * 4;
    p = (char*)(((uintptr_t)p + 15) & ~(uintptr_t)15);
    short* Weh_h  = (short*)p; p += (size_t)HBLK * KIN_PAD * 2;
    short* Weh_l  = (short*)p; p += (size_t)HBLK * KIN_PAD * 2;
    short* Wcat_h = (short*)p; p += (size_t)HBLK * KCAT * 2;
    short* Wcat_l = (short*)p; p += (size_t)HBLK * KCAT * 2;
    short* Wout_h = (short*)p; p += (size_t)32 * HBLK * 2;
    short* Wout_l = (short*)p; p += (size_t)32 * HBLK * 2;
    short* Wly_h[4]; short* Wly_l[4];
    for (int i = 0; i < 4; ++i) {
        Wly_h[i] = (short*)p;  p += (size_t)HBLK * HBLK * 2;
        Wly_l[i] = (short*)p;  p += (size_t)HBLK * HBLK * 2;
    }

    // ---- CSR by dst (rebuilt every call; ws is poisoned between calls) ----
    const int nScanB = (N + 255) / 256;   // <= 256 for N <= 65536
    zero_counts<<<nScanB, 256, 0, stream>>>(counts, N);
    hist_k<<<(E + 255) / 256, 256, 0, stream>>>(dst, counts, E);
    scan1<<<nScanB, 256, 0, stream>>>(counts, offs, bsums, N);
    scan2<<<1, 256, 0, stream>>>(bsums, nScanB);
    scan3<<<nScanB, 256, 0, stream>>>(offs, cursor, bsums, N, E);
    fill_k<<<(E + 255) / 256, 256, 0, stream>>>(dst, src, cursor, srcs, E);

    // ---- weight split+pack (small) ----
    split_w_pack<<<(HBLK * KIN_PAD + 255) / 256, 256, 0, stream>>>(
        W_eh, IN_DIM, IN_DIM, HBLK, Weh_h, Weh_l, HBLK, KIN_PAD);
    split_w_pack<<<(HBLK * KCAT + 255) / 256, 256, 0, stream>>>(
        W_cat, KCAT, KCAT, HBLK, Wcat_h, Wcat_l, HBLK, KCAT);
    split_w_pack<<<(32 * HBLK + 255) / 256, 256, 0, stream>>>(
        W_out, HBLK, HBLK, OUTD, Wout_h, Wout_l, 32, HBLK);
    {
        const float* Wly[4] = {Ws1, Wf1, Ws2, Wf2};
        for (int i = 0; i < 4; ++i)
            split_w_pack<<<(HBLK * HBLK + 255) / 256, 256, 0, stream>>>(
                Wly[i], HBLK, HBLK, HBLK, Wly_h[i], Wly_l[i], HBLK, HBLK);
    }

    const int gGrid = (N + 63) / 64;
    const int n4 = (N + 3) / 4;
    // ---- front GEMM: h0 = feats @ W_eh^T + b_eh ----
    gemm_mfma<<<dim3(gGrid, 1), 256, 0, stream>>>(
        feats, IN_DIM, IN_DIM, nullptr, 0, IN_DIM, KIN_PAD,
        Weh_h, Weh_l, nullptr, nullptr, b_eh, h0, nullptr, nullptr, N, 0);
    // ---- concat GEMM: hin = relu([maps | h0] @ W_cat^T + b_cat) ----
    gemm_mfma<<<dim3(gGrid, 1), 256, 0, stream>>>(
        maps, MAPD, MAPD, h0, HBLK, KCAT, KCAT,
        Wcat_h, Wcat_l, nullptr, nullptr, b_cat, hin, nullptr, nullptr, N, 1);

    // ---- GAT layer 1: hin -> hout ----
    gemm_mfma<<<dim3(gGrid, 2), 256, 0, stream>>>(
        hin, HBLK, HBLK, nullptr, 0, HBLK, HBLK,
        Wly_h[0], Wly_l[0], Wly_h[1], Wly_l[1], nullptr, hs, zb, zh, N, 0);
    compute_s<<<n4, 256, 0, stream>>>(zb, a1, ssrc, sdst, N);
    node_mw<<<n4, 256, 0, stream>>>(ssrc, sdst, offs, srcs, wgt, N);
    gat_gather<<<n4, 256, 0, stream>>>(hin, hs, zh, wgt, offs, srcs, hout, N);

    // ---- GAT layer 2: hout -> hin ----
    gemm_mfma<<<dim3(gGrid, 2), 256, 0, stream>>>(
        hout, HBLK, HBLK, nullptr, 0, HBLK, HBLK,
        Wly_h[2], Wly_l[2], Wly_h[3], Wly_l[3], nullptr, hs, zb, zh, N, 0);
    compute_s<<<n4, 256, 0, stream>>>(zb, a2, ssrc, sdst, N);
    node_mw<<<n4, 256, 0, stream>>>(ssrc, sdst, offs, srcs, wgt, N);
    gat_gather<<<n4, 256, 0, stream>>>(hout, hs, zh, wgt, offs, srcs, hin, N);

    // ---- output projection (MFMA) ----
    gemm_out<<<gGrid, 256, 0, stream>>>(hin, Wout_h, Wout_l, b_out, (float*)d_out, N, OUTD);
}

// Round 13
// 327.136 us; speedup vs baseline: 1.3740x; 1.0562x over previous
//
#include <hip/hip_runtime.h>

#define HBLK 128  // hidden width, fixed by problem

typedef __attribute__((ext_vector_type(8))) short s8v;    // 8 bf16 in 4 VGPRs
typedef __attribute__((ext_vector_type(4))) float f32x4;  // MFMA accumulator
typedef __attribute__((ext_vector_type(8))) _Float16 h8f; // 8 fp16 = 16B

// split fp32 into bf16 hi + lo (truncation; residual <= 2^-16 |x|)
__device__ inline void split2(float x, short& h, short& l) {
    unsigned hb = __float_as_uint(x) & 0xFFFF0000u;
    float hf = __uint_as_float(hb);
    float lf = x - hf;
    h = (short)(hb >> 16);
    l = (short)(__float_as_uint(lf) >> 16);
}

__device__ inline void split8(const float4& a0, const float4& a1, s8v& ah, s8v& al) {
    float vv[8];
    *(float4*)&vv[0] = a0;
    *(float4*)&vv[4] = a1;
#pragma unroll
    for (int e = 0; e < 8; ++e) {
        short hh, ll;
        split2(vv[e], hh, ll);
        ah[e] = hh;
        al[e] = ll;
    }
}

// ---------------- CSR build ----------------
__global__ void zero_counts(int* counts, int n) {
    int i = blockIdx.x * 256 + threadIdx.x;
    if (i < n) counts[i] = 0;
}

__global__ void hist_k(const int* __restrict__ dst, int* counts, int E) {
    int e = blockIdx.x * 256 + threadIdx.x;
    if (e < E) atomicAdd(&counts[dst[e]], 1);
}

// ---- parallel exclusive scan, 3 phases (N up to 256*256) ----
__global__ void scan1(const int* __restrict__ counts, int* __restrict__ offs,
                      int* __restrict__ bsums, int n) {
    __shared__ int lds[256];
    const int t = threadIdx.x;
    const int i = blockIdx.x * 256 + t;
    const int v = (i < n) ? counts[i] : 0;
    lds[t] = v;
    __syncthreads();
    for (int off = 1; off < 256; off <<= 1) {
        int add = (t >= off) ? lds[t - off] : 0;
        __syncthreads();
        lds[t] += add;
        __syncthreads();
    }
    if (i < n) offs[i] = lds[t] - v;          // exclusive within block
    if (t == 255) bsums[blockIdx.x] = lds[255];
}

__global__ void scan2(int* __restrict__ bsums, int nb) {
    __shared__ int lds[256];
    const int t = threadIdx.x;
    const int v = (t < nb) ? bsums[t] : 0;
    lds[t] = v;
    __syncthreads();
    for (int off = 1; off < 256; off <<= 1) {
        int add = (t >= off) ? lds[t - off] : 0;
        __syncthreads();
        lds[t] += add;
        __syncthreads();
    }
    if (t < nb) bsums[t] = lds[t] - v;        // exclusive block prefix
}

__global__ void scan3(int* __restrict__ offs, int* __restrict__ cursor,
                      const int* __restrict__ bsums, int n, int E) {
    const int i = blockIdx.x * 256 + threadIdx.x;
    if (i < n) {
        int v = offs[i] + bsums[blockIdx.x];
        offs[i] = v;
        cursor[i] = v;
    }
    if (i == 0) offs[n] = E;                  // total: every edge has a dst
}

// single scattered store carrying the payload: src_sorted[p] = src[e]
__global__ void fill_k(const int* __restrict__ dst, const int* __restrict__ src,
                       int* cursor, int* __restrict__ src_sorted, int E) {
    int e = blockIdx.x * 256 + threadIdx.x;
    if (e < E) {
        int p = atomicAdd(&cursor[dst[e]], 1);
        if (p >= 0 && p < E) src_sorted[p] = src[e];
    }
}

// ---------------- weight split + pack into MFMA-fragment order ----------------
// Chunk-major: off = ((chunk*(C/16) + j)*64 + lane)*8 + t; chunk c of a C-col
// weight occupies a contiguous (C/16)*1024-short block -> stage-able to LDS.
// Pads k >= kin and c >= cin with zeros.
__global__ void split_w_pack(const float* __restrict__ W, int ldw, int kin, int cin,
                             short* __restrict__ dh, short* __restrict__ dl,
                             int C, int K) {
    long i = (long)blockIdx.x * 256 + threadIdx.x;
    if (i >= (long)C * K) return;
    int c = (int)(i / K), k = (int)(i % K);
    float x = (k < kin && c < cin) ? W[(long)c * ldw + k] : 0.f;
    short h, l;
    split2(x, h, l);
    int nj = C >> 4;
    int j = c >> 4, l16 = c & 15;
    int chunk = k >> 5, quad = (k >> 3) & 3, t = k & 7;
    long off = (((long)(chunk * nj + j) * 64) + quad * 16 + l16) * 8 + t;
    dh[off] = h;
    dl[off] = l;
}

// ---------------- split-fp32 MFMA GEMM, LDS-staged W, double-buffered ----------------
// If avec != null (dual y==1 branch): fused attention-score epilogue computes
// s_src[gr] = z_row . avec[0:128], s_dst[gr] = z_row . avec[128:256] in-register
// (16-lane shfl_xor reduction over the wave's column groups) — no zb round-trip.
__global__ __launch_bounds__(256, 2) void gemm_mfma(
    const float* __restrict__ A1, int lda1, int K1,
    const float* __restrict__ A2, int lda2, int Kin,
    int K,
    const short* __restrict__ W1h, const short* __restrict__ W1l,
    const short* __restrict__ W2h, const short* __restrict__ W2l,
    const float* __restrict__ bias,
    float* __restrict__ C1f, float* __restrict__ C2f,
    _Float16* __restrict__ Czh,
    const float* __restrict__ avec,
    float* __restrict__ sOut, float* __restrict__ dOut,
    int M, int relu)
{
    __shared__ short lds_h[2][4096];   // 8 KB per buffer (one 32-k chunk, hi)
    __shared__ short lds_l[2][4096];   // 8 KB per buffer (lo)
    const short* __restrict__ Wh = blockIdx.y ? W2h : W1h;
    const short* __restrict__ Wl = blockIdx.y ? W2l : W1l;
    float* __restrict__ Cf = blockIdx.y ? C2f : C1f;
    _Float16* __restrict__ Ch16 = blockIdx.y ? Czh : nullptr;
    const float* __restrict__ av = blockIdx.y ? avec : nullptr;
    const int tid = threadIdx.x;
    const int wv = tid >> 6;
    const int lane = tid & 63;
    const int l16 = lane & 15;
    const int quad = lane >> 4;
    const int m0 = blockIdx.x * 64 + wv * 16;   // this wave's 16-row tile
    int ra = m0 + l16;
    if (ra >= M) ra = M - 1;                    // clamp loads; stores guarded
    const long r1 = (long)ra * lda1;
    const long r2 = (long)ra * lda2;
    const int NC = K >> 5;                      // 32-k chunks

    f32x4 acc[8];
#pragma unroll
    for (int j = 0; j < 8; ++j) acc[j] = (f32x4){0.f, 0.f, 0.f, 0.f};

#define LOAD_A_RAW(dst0, dst1, kb)                                              \
    {                                                                           \
        const int col0 = (kb) + quad * 8;                                       \
        if (col0 < K1) {                                                        \
            const float* ap = A1 + r1 + col0;                                   \
            dst0 = *(const float4*)ap;                                          \
            dst1 = *(const float4*)(ap + 4);                                    \
        } else if (col0 < Kin) {                                                \
            const float* ap = A2 + r2 + (col0 - K1);                            \
            dst0 = *(const float4*)ap;                                          \
            dst1 = *(const float4*)(ap + 4);                                    \
        } else {                                                                \
            dst0 = make_float4(0.f, 0.f, 0.f, 0.f);                             \
            dst1 = make_float4(0.f, 0.f, 0.f, 0.f);                             \
        }                                                                       \
    }

    // prologue: stage chunk 0 into buffer 0 (8 KB hi + 8 KB lo; 32 B/thread each)
    {
        const int4* gh = (const int4*)Wh;
        const int4* gl = (const int4*)Wl;
        int4* bh = (int4*)lds_h[0];
        int4* bl = (int4*)lds_l[0];
        bh[tid * 2] = gh[tid * 2];
        bh[tid * 2 + 1] = gh[tid * 2 + 1];
        bl[tid * 2] = gl[tid * 2];
        bl[tid * 2 + 1] = gl[tid * 2 + 1];
    }
    float4 ac0, ac1, an0, an1;
    LOAD_A_RAW(ac0, ac1, 0)
    __syncthreads();

    for (int c = 0; c < NC; ++c) {
        const int nb = c & 1, fb = nb ^ 1;
        // prefetch next W chunk global -> regs
        int4 nh0, nh1, nl0, nl1;
        const bool more = (c + 1 < NC);
        if (more) {
            const int4* gh = (const int4*)(Wh + (long)(c + 1) * 4096);
            const int4* gl = (const int4*)(Wl + (long)(c + 1) * 4096);
            nh0 = gh[tid * 2];
            nh1 = gh[tid * 2 + 1];
            nl0 = gl[tid * 2];
            nl1 = gl[tid * 2 + 1];
        }
        // prefetch next A chunk
        LOAD_A_RAW(an0, an1, more ? (c + 1) * 32 : 0)

        // compute chunk c from LDS buffer nb
        s8v ah, al;
        split8(ac0, ac1, ah, al);
#pragma unroll
        for (int j = 0; j < 8; ++j) {
            const s8v whf = *(const s8v*)&lds_h[nb][(j * 64 + lane) * 8];
            const s8v wlf = *(const s8v*)&lds_l[nb][(j * 64 + lane) * 8];
            acc[j] = __builtin_amdgcn_mfma_f32_16x16x32_bf16(ah, whf, acc[j], 0, 0, 0);
            acc[j] = __builtin_amdgcn_mfma_f32_16x16x32_bf16(ah, wlf, acc[j], 0, 0, 0);
            acc[j] = __builtin_amdgcn_mfma_f32_16x16x32_bf16(al, whf, acc[j], 0, 0, 0);
        }

        // write prefetched chunk into the other buffer (read last iter, free now)
        if (more) {
            int4* bh = (int4*)lds_h[fb];
            int4* bl = (int4*)lds_l[fb];
            bh[tid * 2] = nh0;
            bh[tid * 2 + 1] = nh1;
            bl[tid * 2] = nl0;
            bl[tid * 2 + 1] = nl1;
        }
        __syncthreads();
        ac0 = an0; ac1 = an1;
    }

    // C/D layout: col = lane&15, row = quad*4 + reg  (verified m89/m91)
#pragma unroll
    for (int r = 0; r < 4; ++r) {
        const int gr = m0 + quad * 4 + r;
        if (gr >= M) continue;
#pragma unroll
        for (int j = 0; j < 8; ++j) {
            const int col = j * 16 + l16;
            float v = acc[j][r];
            if (bias) v += bias[col];
            if (relu) v = fmaxf(v, 0.f);
            if (Cf) Cf[(long)gr * HBLK + col] = v;
            if (Ch16) Ch16[(long)gr * HBLK + col] = (_Float16)v;
        }
    }

    // fused attention-score epilogue (dual y==1 branch only)
    if (av) {
        float av0[8], av1[8];
#pragma unroll
        for (int j = 0; j < 8; ++j) {
            av0[j] = av[j * 16 + l16];
            av1[j] = av[128 + j * 16 + l16];
        }
#pragma unroll
        for (int r = 0; r < 4; ++r) {
            float ssp = 0.f, sdp = 0.f;
#pragma unroll
            for (int j = 0; j < 8; ++j) {
                const float v = acc[j][r];
                ssp += v * av0[j];
                sdp += v * av1[j];
            }
#pragma unroll
            for (int off = 1; off < 16; off <<= 1) {
                ssp += __shfl_xor(ssp, off);
                sdp += __shfl_xor(sdp, off);
            }
            const int gr = m0 + quad * 4 + r;
            if (l16 == 0 && gr < M) {
                sOut[gr] = ssp;
                dOut[gr] = sdp;
            }
        }
    }
#undef LOAD_A_RAW
}

// ---------------- output projection via MFMA: out[M x OUTD] = A @ Wout^T + b ----------------
__global__ __launch_bounds__(256) void gemm_out(
    const float* __restrict__ A,
    const short* __restrict__ Wh, const short* __restrict__ Wl,
    const float* __restrict__ bias, float* __restrict__ out,
    int M, int OUTD)
{
    __shared__ short lh[4096], ll[4096];
    const int tid = threadIdx.x;
    {
        const int4* gh = (const int4*)Wh;
        const int4* gl = (const int4*)Wl;
        int4* bh = (int4*)lh;
        int4* bl = (int4*)ll;
        bh[tid * 2] = gh[tid * 2];
        bh[tid * 2 + 1] = gh[tid * 2 + 1];
        bl[tid * 2] = gl[tid * 2];
        bl[tid * 2 + 1] = gl[tid * 2 + 1];
    }
    const int wv = tid >> 6;
    const int lane = tid & 63;
    const int l16 = lane & 15;
    const int quad = lane >> 4;
    const int m0 = blockIdx.x * 64 + wv * 16;
    int ra = m0 + l16;
    if (ra >= M) ra = M - 1;
    const float* arow = A + (long)ra * HBLK + quad * 8;

    f32x4 acc[2];
    acc[0] = (f32x4){0.f, 0.f, 0.f, 0.f};
    acc[1] = (f32x4){0.f, 0.f, 0.f, 0.f};
    __syncthreads();

#pragma unroll
    for (int c = 0; c < 4; ++c) {
        const float4 a0 = *(const float4*)(arow + c * 32);
        const float4 a1 = *(const float4*)(arow + c * 32 + 4);
        s8v ah, al;
        split8(a0, a1, ah, al);
#pragma unroll
        for (int j = 0; j < 2; ++j) {
            const s8v whf = *(const s8v*)&lh[((c * 2 + j) * 64 + lane) * 8];
            const s8v wlf = *(const s8v*)&ll[((c * 2 + j) * 64 + lane) * 8];
            acc[j] = __builtin_amdgcn_mfma_f32_16x16x32_bf16(ah, whf, acc[j], 0, 0, 0);
            acc[j] = __builtin_amdgcn_mfma_f32_16x16x32_bf16(ah, wlf, acc[j], 0, 0, 0);
            acc[j] = __builtin_amdgcn_mfma_f32_16x16x32_bf16(al, whf, acc[j], 0, 0, 0);
        }
    }

#pragma unroll
    for (int r = 0; r < 4; ++r) {
        const int gr = m0 + quad * 4 + r;
        if (gr >= M) continue;
#pragma unroll
        for (int j = 0; j < 2; ++j) {
            const int col = j * 16 + l16;
            if (col < OUTD)
                out[(long)gr * OUTD + col] = acc[j][r] + bias[col];
        }
    }
}

// ---------------- fused softmax + weighted gather; one wave per node ----------------
// pass 1: online max/sum over incoming edges (64-lane stride).
// pass 2: 4 groups of 16 lanes; lane owns cols [8l, 8l+7] (16B loads); group g
// handles edges beg+g, beg+g+4, ... (2-way unroll, 8 outstanding gathers/wave);
// w recomputed per edge from L2-hot s_src (replaces the wgt round-trip).
__global__ void gat_gather(const float* __restrict__ h_in, const float* __restrict__ hs,
                           const _Float16* __restrict__ zh,
                           const float* __restrict__ s_src, const float* __restrict__ s_dst,
                           const int* __restrict__ offs, const int* __restrict__ srcs,
                           float* __restrict__ h_out, int N) {
    const int wave = threadIdx.x >> 6;
    const int lane = threadIdx.x & 63;
    const int n = blockIdx.x * 4 + wave;
    if (n >= N) return;
    const int g = lane >> 4, l = lane & 15;
    const int beg = offs[n], end = offs[n + 1];

    float acc[8] = {};
    if (end > beg) {
        const float sd = s_dst[n];
        // pass 1: online softmax stats
        float m = -INFINITY, s = 0.f;
        for (int i = beg + lane; i < end; i += 64) {
            float e = sd + s_src[srcs[i]];
            e = e > 0.f ? e : 0.01f * e;
            float nm = fmaxf(m, e);
            s = s * __expf(m - nm) + __expf(e - nm);
            m = nm;
        }
#pragma unroll
        for (int off = 32; off > 0; off >>= 1) {
            float m2 = __shfl_down(m, off);
            float s2 = __shfl_down(s, off);
            if (m2 > m) {
                float t = m; m = m2; m2 = t;
                float ts = s; s = s2; s2 = ts;
            }
            s = (m == -INFINITY) ? 0.f : s + s2 * __expf(m2 - m);
        }
        m = __shfl(m, 0);
        s = __shfl(s, 0);
        const float inv = 1.f / fmaxf(s, 1e-16f);

        // pass 2: weighted gather, weight recomputed per edge
        int i = beg + g;
        for (; i + 4 < end; i += 8) {
            const int s0 = srcs[i];
            const int s1 = srcs[i + 4];
            float e0 = sd + s_src[s0];
            float e1 = sd + s_src[s1];
            e0 = e0 > 0.f ? e0 : 0.01f * e0;
            e1 = e1 > 0.f ? e1 : 0.01f * e1;
            const float w0 = __expf(e0 - m) * inv;
            const float w1 = __expf(e1 - m) * inv;
            const h8f z0 = *(const h8f*)(zh + (long)s0 * HBLK + 8 * l);
            const h8f z1 = *(const h8f*)(zh + (long)s1 * HBLK + 8 * l);
#pragma unroll
            for (int e = 0; e < 8; ++e)
                acc[e] += w0 * (float)z0[e] + w1 * (float)z1[e];
        }
        if (i < end) {
            const int s0 = srcs[i];
            float e0 = sd + s_src[s0];
            e0 = e0 > 0.f ? e0 : 0.01f * e0;
            const float w0 = __expf(e0 - m) * inv;
            const h8f z0 = *(const h8f*)(zh + (long)s0 * HBLK + 8 * l);
#pragma unroll
            for (int e = 0; e < 8; ++e)
                acc[e] += w0 * (float)z0[e];
        }
        // combine the 4 groups (same col mapping)
#pragma unroll
        for (int e = 0; e < 8; ++e) {
            acc[e] += __shfl_down(acc[e], 32);
            acc[e] += __shfl_down(acc[e], 16);
        }
    }

    if (g == 0) {
        const long base = (long)n * HBLK + 8 * l;
        const float4 hi0 = *(const float4*)(h_in + base);
        const float4 hi1 = *(const float4*)(h_in + base + 4);
        float o[8];
        if (end > beg) {
            const float4 hv0 = *(const float4*)(hs + base);
            const float4 hv1 = *(const float4*)(hs + base + 4);
            const float* hip = (const float*)&hi0;
            const float* hvp = (const float*)&hv0;
#pragma unroll
            for (int e = 0; e < 4; ++e) o[e] = hip[e] + hvp[e] + acc[e];
            const float* hip1 = (const float*)&hi1;
            const float* hvp1 = (const float*)&hv1;
#pragma unroll
            for (int e = 0; e < 4; ++e) o[4 + e] = hip1[e] + hvp1[e] + acc[4 + e];
        } else {  // DGL leaves h at h_in; residual doubles it
            const float* hip = (const float*)&hi0;
            const float* hip1 = (const float*)&hi1;
#pragma unroll
            for (int e = 0; e < 4; ++e) o[e] = 2.f * hip[e];
#pragma unroll
            for (int e = 0; e < 4; ++e) o[4 + e] = 2.f * hip1[e];
        }
        *(float4*)(h_out + base) = *(float4*)&o[0];
        *(float4*)(h_out + base + 4) = *(float4*)&o[4];
    }
}

extern "C" void kernel_launch(void* const* d_in, const int* in_sizes, int n_in,
                              void* d_out, int out_size, void* d_ws, size_t ws_size,
                              hipStream_t stream) {
    const float* feats = (const float*)d_in[0];
    const float* maps  = (const float*)d_in[2];
    const int* src = (const int*)d_in[4];
    const int* dst = (const int*)d_in[5];
    const float* W_eh  = (const float*)d_in[6];
    const float* b_eh  = (const float*)d_in[7];
    const float* W_cat = (const float*)d_in[10];
    const float* b_cat = (const float*)d_in[11];
    const float* Ws1 = (const float*)d_in[12];
    const float* Wf1 = (const float*)d_in[13];
    const float* a1  = (const float*)d_in[14];
    const float* Ws2 = (const float*)d_in[15];
    const float* Wf2 = (const float*)d_in[16];
    const float* a2  = (const float*)d_in[17];
    const float* W_out = (const float*)d_in[18];
    const float* b_out = (const float*)d_in[19];

    const int N = in_sizes[3];            // snorm_n is (N,1)
    const int E = in_sizes[4];
    const int IN_DIM = in_sizes[0] / N;   // 24
    const int MAPD = in_sizes[2] / N;     // 512
    const int OUTD = in_sizes[19];        // 24
    const int KCAT = MAPD + HBLK;         // 640 (multiple of 32)
    const int KIN_PAD = 32;               // 24 padded to one K-chunk

    // ---- workspace layout ----
    char* p = (char*)d_ws;
    const size_t NH = (size_t)N * HBLK;
    float* hin  = (float*)p;  p += NH * 4;
    float* h0   = (float*)p;  p += NH * 4;
    float* hs   = (float*)p;  p += NH * 4;
    float* hout = (float*)p;  p += NH * 4;
    _Float16* zh = (_Float16*)p; p += NH * 2;
    float* ssrc = (float*)p;  p += (size_t)N * 4;
    float* sdst = (float*)p;  p += (size_t)N * 4;
    int* counts = (int*)p;    p += (size_t)N * 4;
    int* cursor = (int*)p;    p += (size_t)N * 4;
    int* offs   = (int*)p;    p += (size_t)(N + 1) * 4;
    int* srcs   = (int*)p;    p += (size_t)E * 4;   // src payload, dst-sorted
    int* bsums  = (int*)p;    p += 256 * 4;
    p = (char*)(((uintptr_t)p + 15) & ~(uintptr_t)15);
    short* Weh_h  = (short*)p; p += (size_t)HBLK * KIN_PAD * 2;
    short* Weh_l  = (short*)p; p += (size_t)HBLK * KIN_PAD * 2;
    short* Wcat_h = (short*)p; p += (size_t)HBLK * KCAT * 2;
    short* Wcat_l = (short*)p; p += (size_t)HBLK * KCAT * 2;
    short* Wout_h = (short*)p; p += (size_t)32 * HBLK * 2;
    short* Wout_l = (short*)p; p += (size_t)32 * HBLK * 2;
    short* Wly_h[4]; short* Wly_l[4];
    for (int i = 0; i < 4; ++i) {
        Wly_h[i] = (short*)p;  p += (size_t)HBLK * HBLK * 2;
        Wly_l[i] = (short*)p;  p += (size_t)HBLK * HBLK * 2;
    }

    // ---- CSR by dst (rebuilt every call; ws is poisoned between calls) ----
    const int nScanB = (N + 255) / 256;   // <= 256 for N <= 65536
    zero_counts<<<nScanB, 256, 0, stream>>>(counts, N);
    hist_k<<<(E + 255) / 256, 256, 0, stream>>>(dst, counts, E);
    scan1<<<nScanB, 256, 0, stream>>>(counts, offs, bsums, N);
    scan2<<<1, 256, 0, stream>>>(bsums, nScanB);
    scan3<<<nScanB, 256, 0, stream>>>(offs, cursor, bsums, N, E);
    fill_k<<<(E + 255) / 256, 256, 0, stream>>>(dst, src, cursor, srcs, E);

    // ---- weight split+pack (small) ----
    split_w_pack<<<(HBLK * KIN_PAD + 255) / 256, 256, 0, stream>>>(
        W_eh, IN_DIM, IN_DIM, HBLK, Weh_h, Weh_l, HBLK, KIN_PAD);
    split_w_pack<<<(HBLK * KCAT + 255) / 256, 256, 0, stream>>>(
        W_cat, KCAT, KCAT, HBLK, Wcat_h, Wcat_l, HBLK, KCAT);
    split_w_pack<<<(32 * HBLK + 255) / 256, 256, 0, stream>>>(
        W_out, HBLK, HBLK, OUTD, Wout_h, Wout_l, 32, HBLK);
    {
        const float* Wly[4] = {Ws1, Wf1, Ws2, Wf2};
        for (int i = 0; i < 4; ++i)
            split_w_pack<<<(HBLK * HBLK + 255) / 256, 256, 0, stream>>>(
                Wly[i], HBLK, HBLK, HBLK, Wly_h[i], Wly_l[i], HBLK, HBLK);
    }

    const int gGrid = (N + 63) / 64;
    const int n4 = (N + 3) / 4;
    // ---- front GEMM: h0 = feats @ W_eh^T + b_eh ----
    gemm_mfma<<<dim3(gGrid, 1), 256, 0, stream>>>(
        feats, IN_DIM, IN_DIM, nullptr, 0, IN_DIM, KIN_PAD,
        Weh_h, Weh_l, nullptr, nullptr, b_eh, h0, nullptr, nullptr,
        nullptr, nullptr, nullptr, N, 0);
    // ---- concat GEMM: hin = relu([maps | h0] @ W_cat^T + b_cat) ----
    gemm_mfma<<<dim3(gGrid, 1), 256, 0, stream>>>(
        maps, MAPD, MAPD, h0, HBLK, KCAT, KCAT,
        Wcat_h, Wcat_l, nullptr, nullptr, b_cat, hin, nullptr, nullptr,
        nullptr, nullptr, nullptr, N, 1);

    // ---- GAT layer 1: hin -> hout (dual GEMM w/ fused score epilogue) ----
    gemm_mfma<<<dim3(gGrid, 2), 256, 0, stream>>>(
        hin, HBLK, HBLK, nullptr, 0, HBLK, HBLK,
        Wly_h[0], Wly_l[0], Wly_h[1], Wly_l[1], nullptr, hs, nullptr, zh,
        a1, ssrc, sdst, N, 0);
    gat_gather<<<n4, 256, 0, stream>>>(hin, hs, zh, ssrc, sdst, offs, srcs, hout, N);

    // ---- GAT layer 2: hout -> hin ----
    gemm_mfma<<<dim3(gGrid, 2), 256, 0, stream>>>(
        hout, HBLK, HBLK, nullptr, 0, HBLK, HBLK,
        Wly_h[2], Wly_l[2], Wly_h[3], Wly_l[3], nullptr, hs, nullptr, zh,
        a2, ssrc, sdst, N, 0);
    gat_gather<<<n4, 256, 0, stream>>>(hout, hs, zh, ssrc, sdst, offs, srcs, hin, N);

    // ---- output projection (MFMA) ----
    gemm_out<<<gGrid, 256, 0, stream>>>(hin, Wout_h, Wout_l, b_out, (float*)d_out, N, OUTD);
}